// Round 17
// baseline (93.008 us; speedup 1.0000x reference)
//
#include <hip/hip_runtime.h>
#include <cstdint>

// Problem constants (B=8, C=80, H=W=128, K=100, kernel=3, num_dets=1000)
#define NB    8
#define NC    80
#define HH    128
#define WW    128
#define HW    16384
#define CHW   1310720
#define KTOP  100
#define NDET  1000
#define NPAIR 10000
#define CAP   4096
#define ACAP  2048
#define NBINS 4096        // fallback hist: 12-bit bins over sigmoid bits (>>19)
#define NSEG  160
#define VTHR  3.0f        // fixed conservative raw threshold (exactness VERIFIED by count)

// ---- workspace layout (bytes) ----
#define OFF_CCNT   0                         // int[24*32] fast-path counts (128B apart)
#define OFF_CCNT2  3072                      // int[24*32] fallback counts
#define OFF_HIST   6144                      // u32[24][4096] (fallback only)
#define ZERO_BYTES 399360                    // ccnt+ccnt2+hist
#define OFF_THR    399360                    // int[32]
#define OFF_CAND   399488                    // u64[24][4096]
#define OFF_CS     1185920                   // float[2400]
#define OFF_CX     1195520
#define OFF_CY     1205120
#define OFF_CE     1214720
#define OFF_CCLS   1224320                   // int[2400]
#define WS_NEEDED  1233920                   // ~1.2 MB

// branchless, bit-identical to jax.nn.sigmoid's two-branch form
__device__ __forceinline__ float sigmoidf(float x) {
    float e = expf(-fabsf(x));
    return (x >= 0.f ? 1.f : e) / (1.f + e);
}

// ---- kernel 1: NMS stencil -> direct candidate emission (v >= VTHR) ----
// NO LDS, NO barriers, NO histogram. Exact count accumulated; exactness of the
// fixed threshold is verified downstream (100 <= cnt <= CAP), else fallback.
__global__ void __launch_bounds__(256) k_nms(
        const float* __restrict__ tl, const float* __restrict__ br,
        const float* __restrict__ ct,
        uint64_t* __restrict__ cand, int* __restrict__ ccnt) {
    int tid = threadIdx.x;
    int bid = blockIdx.x;
    int bc = bid / NSEG;
    int seg = bid - bc * NSEG;
    int t = bc >> 3; int b = bc & 7;
    const float* heat = (t == 0) ? tl : (t == 1) ? br : ct;
    int chan = seg >> 1;
    int half = seg & 1;
    const float* cb = heat + (size_t)b * CHW + (size_t)chan * HW;
    int lane = tid & 63;
    int wid = tid >> 6;
    int band = (wid << 1) + (lane >> 5);             // 0..7
    int ybase = half * 64 + band * 8;                // 0..120
    int x0 = (lane & 31) << 2;
    const float NEG = -__builtin_inff();

    // 10 unconditional loads (clamped row), pinned live
    float4 L[10];
    #pragma unroll
    for (int r = 0; r < 10; ++r) {
        int yy = ybase - 1 + r;
        int yc = min(max(yy, 0), HH - 1);
        L[r] = *(const float4*)(cb + yc * WW + x0);
    }
    #pragma unroll
    for (int r = 0; r < 10; ++r)
        asm volatile("" : "+v"(L[r].x), "+v"(L[r].y), "+v"(L[r].z), "+v"(L[r].w));
    if (ybase == 0)       L[0] = make_float4(NEG, NEG, NEG, NEG);
    if (ybase == HH - 8)  L[9] = make_float4(NEG, NEG, NEG, NEG);

    // stencil; mask2 bit = local-max AND value >= VTHR (candidate)
    uint32_t mask2 = 0;
    #pragma unroll
    for (int j = 0; j < 8; ++j) {
        float c0 = fmaxf(fmaxf(L[j].x, L[j+1].x), L[j+2].x);
        float c1 = fmaxf(fmaxf(L[j].y, L[j+1].y), L[j+2].y);
        float c2 = fmaxf(fmaxf(L[j].z, L[j+1].z), L[j+2].z);
        float c3 = fmaxf(fmaxf(L[j].w, L[j+1].w), L[j+2].w);
        float cl = __shfl_up(c3, 1);
        float cr = __shfl_down(c0, 1);
        if (x0 == 0)      cl = NEG;
        if (x0 == WW - 4) cr = NEG;
        if (fmaxf(fmaxf(cl, c0), c1) == L[j+1].x && L[j+1].x >= VTHR) mask2 |= 1u << (j*4+0);
        if (fmaxf(fmaxf(c0, c1), c2) == L[j+1].y && L[j+1].y >= VTHR) mask2 |= 1u << (j*4+1);
        if (fmaxf(fmaxf(c1, c2), c3) == L[j+1].z && L[j+1].z >= VTHR) mask2 |= 1u << (j*4+2);
        if (fmaxf(fmaxf(c2, c3), cr) == L[j+1].w && L[j+1].w >= VTHR) mask2 |= 1u << (j*4+3);
    }

    // wave-level compaction: ~2.5 candidates/wave expected
    int cnt = __popc(mask2);
    int incl = cnt;
    #pragma unroll
    for (int d = 1; d < 64; d <<= 1) {
        int u = __shfl_up(incl, d);
        if (lane >= d) incl += u;
    }
    int total = __shfl(incl, 63);
    if (total) {
        int gbase = 0;
        if (lane == 0) gbase = atomicAdd(&ccnt[bc * 32], total);  // exact count
        gbase = __shfl(gbase, 0);
        int pos = gbase + incl - cnt;
        int ib = chan * HW + ybase * WW + x0;
        uint64_t* cd = cand + (size_t)bc * CAP;
        #pragma unroll
        for (int j = 0; j < 8; ++j) {
            #pragma unroll
            for (int p = 0; p < 4; ++p) {
                if (mask2 & (1u << (j * 4 + p))) {
                    float v = (p == 0) ? L[j+1].x : (p == 1) ? L[j+1].y
                            : (p == 2) ? L[j+1].z : L[j+1].w;
                    uint32_t bt = __float_as_uint(sigmoidf(v));
                    int idx = ib + j * WW + p;
                    if (pos < CAP)
                        cd[pos] = ((uint64_t)bt << 32) | (uint32_t)(~(uint32_t)idx);
                    ++pos;
                }
            }
        }
    }
}

// on-the-fly key for the fallback (never expected on this input)
__device__ uint64_t key_at(const float* __restrict__ hb, int i) {
    float v = hb[i];
    int rem = i & (HW - 1);
    int y = rem >> 7, x = rem & (WW - 1);
    bool mx = true;
    if (y > 0) {
        if (x > 0      && hb[i - WW - 1] > v) mx = false;
        if (              hb[i - WW    ] > v) mx = false;
        if (x < WW - 1 && hb[i - WW + 1] > v) mx = false;
    }
    if (x > 0      && hb[i - 1] > v) mx = false;
    if (x < WW - 1 && hb[i + 1] > v) mx = false;
    if (y < HH - 1) {
        if (x > 0      && hb[i + WW - 1] > v) mx = false;
        if (              hb[i + WW    ] > v) mx = false;
        if (x < WW - 1 && hb[i + WW + 1] > v) mx = false;
    }
    if (!mx) return 0;
    return ((uint64_t)__float_as_uint(sigmoidf(v)) << 32) | (uint32_t)(~(uint32_t)i);
}

__device__ __forceinline__ bool fast_ok(const int* ccnt, int bc) {
    int n = ccnt[bc * 32];
    return (n >= KTOP) && (n <= CAP);
}

// ---- fallback kernel A: LDS histogram of all survivors (early-exits) ----
__global__ void __launch_bounds__(256) fb_hist(
        const int* __restrict__ ccnt,
        const float* __restrict__ tl, const float* __restrict__ br,
        const float* __restrict__ ct, uint32_t* __restrict__ hist) {
    int bc = blockIdx.y;
    if (fast_ok(ccnt, bc)) return;
    __shared__ uint32_t lh[NBINS];
    for (int i = threadIdx.x; i < NBINS; i += 256) lh[i] = 0;
    __syncthreads();
    int t = bc >> 3; int b = bc & 7;
    const float* heat = (t == 0) ? tl : (t == 1) ? br : ct;
    const float* hb = heat + (size_t)b * CHW;
    for (int i = blockIdx.x * 256 + threadIdx.x; i < CHW; i += 32 * 256) {
        uint64_t k = key_at(hb, i);
        if (k) atomicAdd(&lh[(uint32_t)(k >> 51)], 1u);
    }
    __syncthreads();
    uint32_t* gh = hist + (size_t)bc * NBINS;
    for (int i = threadIdx.x; i < NBINS; i += 256) {
        uint32_t c = lh[i];
        if (c) atomicAdd(&gh[i], c);
    }
}

// ---- fallback kernel B: threshold (early-exits) ----
__global__ void __launch_bounds__(256) fb_thresh(
        const int* __restrict__ ccnt, const uint32_t* __restrict__ hist,
        int* __restrict__ thr) {
    int bc = blockIdx.x;
    if (fast_ok(ccnt, bc)) return;
    __shared__ uint32_t csum[256];
    const uint32_t* h = hist + (size_t)bc * NBINS;
    int tid = threadIdx.x;
    uint32_t bins[16];
    #pragma unroll
    for (int i = 0; i < 16; ++i) bins[i] = h[tid * 16 + i];
    if (tid == 0) bins[0] = 0;
    uint32_t s = 0;
    #pragma unroll
    for (int i = 0; i < 16; ++i) s += bins[i];
    csum[tid] = s;
    __syncthreads();
    for (int step = 1; step < 256; step <<= 1) {
        uint32_t add = (tid + step < 256) ? csum[tid + step] : 0;
        __syncthreads();
        csum[tid] += add;
        __syncthreads();
    }
    uint32_t inc = csum[tid];
    uint32_t above = (tid + 1 < 256) ? csum[tid + 1] : 0;
    if (tid == 0 && inc < KTOP) thr[bc] = 1;
    if (above < KTOP && inc >= KTOP) {
        uint32_t cum = above;
        int T = 1;
        #pragma unroll
        for (int i = 15; i >= 0; --i) {
            cum += bins[i];
            if (cum >= KTOP) { T = tid * 16 + i; break; }
        }
        thr[bc] = T;
    }
}

// ---- fallback kernel C: collect survivors >= T into cand (early-exits) ----
__global__ void __launch_bounds__(256) fb_collect(
        const int* __restrict__ ccnt, const int* __restrict__ thr,
        const float* __restrict__ tl, const float* __restrict__ br,
        const float* __restrict__ ct,
        uint64_t* __restrict__ cand, int* __restrict__ ccnt2) {
    int bc = blockIdx.y;
    if (fast_ok(ccnt, bc)) return;
    int t = bc >> 3; int b = bc & 7;
    const float* heat = (t == 0) ? tl : (t == 1) ? br : ct;
    const float* hb = heat + (size_t)b * CHW;
    int T = thr[bc];
    for (int i = blockIdx.x * 256 + threadIdx.x; i < CHW; i += 32 * 256) {
        uint64_t k = key_at(hb, i);
        if (k && (int)(uint32_t)(k >> 51) >= T) {
            int pc = atomicAdd(&ccnt2[bc * 32], 1);
            if (pc < CAP) cand[(size_t)bc * CAP + pc] = k;
        }
    }
}

// descending bitonic sort of N u64 keys in LDS
template <int N>
__device__ void bitonic_desc(uint64_t* k) {
    for (int kk = 2; kk <= N; kk <<= 1) {
        for (int j = kk >> 1; j > 0; j >>= 1) {
            __syncthreads();
            for (int i = threadIdx.x; i < N; i += blockDim.x) {
                int l = i ^ j;
                if (l > i) {
                    uint64_t a = k[i], b = k[l];
                    bool up = ((i & kk) == 0);
                    if (up ? (a < b) : (a > b)) { k[i] = b; k[l] = a; }
                }
            }
        }
    }
    __syncthreads();
}

// ---- kernel 2: per (tensor,batch) sort candidates, emit top-100 ----
__global__ void __launch_bounds__(1024) k_select(
        const uint64_t* __restrict__ cand, const int* __restrict__ ccnt,
        const int* __restrict__ ccnt2,
        const float* __restrict__ tl_tag, const float* __restrict__ br_tag,
        const float* __restrict__ tl_regr, const float* __restrict__ br_regr,
        const float* __restrict__ ct_regr,
        float* __restrict__ cs, float* __restrict__ cx, float* __restrict__ cy,
        float* __restrict__ ce, int* __restrict__ ccls) {
    __shared__ uint64_t keys[CAP];
    int bc = blockIdx.x; int t = bc >> 3; int b = bc & 7;
    int nf = ccnt[bc * 32];
    bool ok = (nf >= KTOP) && (nf <= CAP);
    int n = ok ? nf : ccnt2[bc * 32];
    if (n > CAP) n = CAP;
    if (n <= 512) {
        for (int i = threadIdx.x; i < 512; i += 1024)
            keys[i] = (i < n) ? cand[(size_t)bc * CAP + i] : 0ull;
        bitonic_desc<512>(keys);
    } else if (n <= 2048) {
        for (int i = threadIdx.x; i < 2048; i += 1024)
            keys[i] = (i < n) ? cand[(size_t)bc * CAP + i] : 0ull;
        bitonic_desc<2048>(keys);
    } else {
        for (int i = threadIdx.x; i < CAP; i += 1024)
            keys[i] = (i < n) ? cand[(size_t)bc * CAP + i] : 0ull;
        bitonic_desc<CAP>(keys);
    }
    if (threadIdx.x < KTOP) {
        uint64_t key = keys[threadIdx.x];
        float s = __uint_as_float((uint32_t)(key >> 32));
        uint32_t idx = ~(uint32_t)key;
        int cls = (int)(idx >> 14);
        int rem = (int)(idx & (HW - 1));
        int y = rem >> 7, x = rem & (WW - 1);
        const float* regr = (t == 0) ? tl_regr : (t == 1) ? br_regr : ct_regr;
        float o0 = regr[((size_t)b * 2 + 0) * HW + rem];
        float o1 = regr[((size_t)b * 2 + 1) * HW + rem];
        float emb = 0.f;
        if (t == 0) emb = tl_tag[(size_t)b * HW + rem];
        else if (t == 1) emb = br_tag[(size_t)b * HW + rem];
        int o = bc * KTOP + threadIdx.x;
        cs[o] = s;
        cx[o] = (float)x + o0;
        cy[o] = (float)y + o1;
        ce[o] = emb;
        ccls[o] = cls;
    }
}

// ---- kernel 3: fused pairwise scoring + final top-1000 + centers ----
__global__ void __launch_bounds__(1024) k_pairfinal(
        const float* __restrict__ cs, const float* __restrict__ cx,
        const float* __restrict__ cy, const float* __restrict__ ce,
        const int* __restrict__ ccls, float* __restrict__ out) {
    int b = blockIdx.x;
    __shared__ float ts[KTOP], tx[KTOP], ty[KTOP], te[KTOP];
    __shared__ int   tc[KTOP];
    __shared__ float bs_[KTOP], bx[KTOP], by[KTOP], be[KTOP];
    __shared__ int   bcl[KTOP];
    __shared__ uint64_t acc[ACAP];
    __shared__ int aidx[ACAP];
    __shared__ int acnt_s;
    int tid = threadIdx.x;
    if (tid == 0) acnt_s = 0;
    if (tid < KTOP) {
        int o = (0 * NB + b) * KTOP + tid;
        ts[tid] = cs[o]; tx[tid] = cx[o]; ty[tid] = cy[o]; te[tid] = ce[o]; tc[tid] = ccls[o];
    } else if (tid >= 512 && tid < 512 + KTOP) {
        int k = tid - 512;
        int o = (1 * NB + b) * KTOP + k;
        bs_[k] = cs[o]; bx[k] = cx[o]; by[k] = cy[o]; be[k] = ce[o]; bcl[k] = ccls[o];
    }
    __syncthreads();
    for (int p = tid; p < NPAIR; p += 1024) {
        int i = p / KTOP, j = p - i * KTOP;
        bool rej = (tc[i] != bcl[j])
                 | (fabsf(te[i] - be[j]) > 0.5f)
                 | (bx[j] < tx[i])
                 | (by[j] < ty[i]);
        if (!rej) {
            float sc = (ts[i] + bs_[j]) * 0.5f;
            int pos = atomicAdd(&acnt_s, 1);
            if (pos < ACAP)
                acc[pos] = ((uint64_t)__float_as_uint(sc) << 32) | (uint32_t)(~(uint32_t)p);
        }
    }
    __syncthreads();
    int m = acnt_s; if (m > ACAP) m = ACAP;
    if (m <= 256) {
        for (int i = tid; i < 256; i += 1024) if (i >= m) acc[i] = 0;
        bitonic_desc<256>(acc);
    } else {
        for (int i = tid; i < ACAP; i += 1024) if (i >= m) acc[i] = 0;
        bitonic_desc<ACAP>(acc);
    }
    for (int i = tid; i < m; i += 1024) aidx[i] = (int)(~(uint32_t)acc[i]);
    __syncthreads();
    for (int d = tid; d < NDET; d += 1024) {
        int p; float sc;
        if (d < m) {
            p = aidx[d];
            sc = __uint_as_float((uint32_t)(acc[d] >> 32));
        } else {
            // (d-m)-th flat pair-index NOT in accepted set, ascending (stable -1 ties)
            int r = d - m;
            int idx = r;
            for (;;) {
                int c = 0;
                for (int a = 0; a < m; ++a) c += (aidx[a] <= idx) ? 1 : 0;
                int ni = r + c;
                if (ni == idx) break;
                idx = ni;
            }
            p = idx; sc = -1.f;
        }
        int i = p / KTOP, j = p - i * KTOP;
        int ot = (0 * NB + b) * KTOP + i;
        int ob = (1 * NB + b) * KTOP + j;
        float* dr = out + ((size_t)b * NDET + d) * 8;
        dr[0] = cx[ot]; dr[1] = cy[ot]; dr[2] = cx[ob]; dr[3] = cy[ob];
        dr[4] = sc; dr[5] = cs[ot]; dr[6] = cs[ob]; dr[7] = (float)ccls[ot];
    }
    if (tid < KTOP) {
        int oc = (2 * NB + b) * KTOP + tid;
        float* cr = out + (size_t)NB * NDET * 8 + ((size_t)b * KTOP + tid) * 4;
        cr[0] = cx[oc]; cr[1] = cy[oc]; cr[2] = (float)ccls[oc]; cr[3] = cs[oc];
    }
}

extern "C" void kernel_launch(void* const* d_in, const int* in_sizes, int n_in,
                              void* d_out, int out_size, void* d_ws, size_t ws_size,
                              hipStream_t stream) {
    const float* tl_heat = (const float*)d_in[0];
    const float* br_heat = (const float*)d_in[1];
    const float* ct_heat = (const float*)d_in[2];
    const float* tl_tag  = (const float*)d_in[3];
    const float* br_tag  = (const float*)d_in[4];
    const float* tl_regr = (const float*)d_in[5];
    const float* br_regr = (const float*)d_in[6];
    const float* ct_regr = (const float*)d_in[7];

    if (ws_size < (size_t)WS_NEEDED) return;   // ~1.2 MB

    char* ws = (char*)d_ws;
    int*      ccnt  = (int*)(ws + OFF_CCNT);
    int*      ccnt2 = (int*)(ws + OFF_CCNT2);
    uint32_t* hist  = (uint32_t*)(ws + OFF_HIST);
    int*      thr   = (int*)(ws + OFF_THR);
    uint64_t* cand  = (uint64_t*)(ws + OFF_CAND);
    float*    cs    = (float*)(ws + OFF_CS);
    float*    cx    = (float*)(ws + OFF_CX);
    float*    cy    = (float*)(ws + OFF_CY);
    float*    ce    = (float*)(ws + OFF_CE);
    int*      ccls  = (int*)(ws + OFF_CCLS);

    hipMemsetAsync(ws, 0, ZERO_BYTES, stream);   // ccnt + ccnt2 + hist

    k_nms<<<24 * NSEG, 256, 0, stream>>>(tl_heat, br_heat, ct_heat, cand, ccnt);
    fb_hist<<<dim3(32, 24), 256, 0, stream>>>(ccnt, tl_heat, br_heat, ct_heat, hist);
    fb_thresh<<<24, 256, 0, stream>>>(ccnt, hist, thr);
    fb_collect<<<dim3(32, 24), 256, 0, stream>>>(ccnt, thr,
                                                 tl_heat, br_heat, ct_heat,
                                                 cand, ccnt2);
    k_select<<<24, 1024, 0, stream>>>(cand, ccnt, ccnt2, tl_tag, br_tag,
                                      tl_regr, br_regr, ct_regr,
                                      cs, cx, cy, ce, ccls);
    k_pairfinal<<<NB, 1024, 0, stream>>>(cs, cx, cy, ce, ccls, (float*)d_out);
}

// Round 18
// 68.082 us; speedup vs baseline: 1.3661x; 1.3661x over previous
//
#include <hip/hip_runtime.h>
#include <cstdint>

// Problem constants (B=8, C=80, H=W=128, K=100, kernel=3, num_dets=1000)
#define NB    8
#define NC    80
#define HH    128
#define WW    128
#define HW    16384
#define CHW   1310720
#define KTOP  100
#define NDET  1000
#define NPAIR 10000
#define CAP   4096
#define ACAP  2048
#define NBINS 4096        // fallback hist: 12-bit bins over sigmoid bits (>>19)
#define VTHR  3.5f        // fixed conservative raw threshold; exactness VERIFIED by count

// ---- workspace layout (bytes) ----
#define OFF_CCNT   0                         // int[24*32] fast-path counts (128B apart)
#define OFF_CCNT2  3072                      // int[24*32] fallback counts
#define OFF_HIST   6144                      // u32[24][4096] (fallback only)
#define ZERO_BYTES 399360                    // ccnt+ccnt2+hist
#define OFF_THR    399360                    // int[32]
#define OFF_CAND   399488                    // u64[24][4096]
#define OFF_CS     1185920                   // float[2400]
#define OFF_CX     1195520
#define OFF_CY     1205120
#define OFF_CE     1214720
#define OFF_CCLS   1224320                   // int[2400]
#define WS_NEEDED  1233920                   // ~1.2 MB

// branchless, bit-identical to jax.nn.sigmoid's two-branch form
__device__ __forceinline__ float sigmoidf(float x) {
    float e = expf(-fabsf(x));
    return (x >= 0.f ? 1.f : e) / (1.f + e);
}

// ---- kernel 1: channel-resident NMS ----
// Block = one (bc, chan) plane. Stage 64KB to LDS via global_load_lds
// (sequential stream, 1.0x amplification), one barrier, stencil from LDS,
// per-survivor atomic emission (v >= VTHR; ~300/bc; exactness checked).
__global__ void __launch_bounds__(512) k_nms(
        const float* __restrict__ tl, const float* __restrict__ br,
        const float* __restrict__ ct,
        uint64_t* __restrict__ cand, int* __restrict__ ccnt) {
    __shared__ float lds[HW];   // 64 KB: the whole 128x128 channel

    int tid = threadIdx.x;
    int bid = blockIdx.x;
    int bc = bid / NC;
    int chan = bid - bc * NC;
    int t = bc >> 3; int b = bc & 7;
    const float* heat = (t == 0) ? tl : (t == 1) ? br : ct;
    const float* cb = heat + (size_t)b * CHW + (size_t)chan * HW;
    int lane = tid & 63;
    int w = tid >> 6;            // wave 0..7

    // ---- stage: 8 x global_load_lds(16B) per wave, linear layout ----
    #pragma unroll
    for (int it = 0; it < 8; ++it) {
        int fbase = (it * 8 + w) * 256;      // floats; wave-uniform LDS base
        __builtin_amdgcn_global_load_lds(
            (const __attribute__((address_space(1))) void*)(cb + fbase + lane * 4),
            (__attribute__((address_space(3))) void*)(&lds[fbase]),
            16, 0, 0);
    }
    asm volatile("s_waitcnt vmcnt(0)" ::: "memory");
    __syncthreads();

    // ---- stencil: thread owns a 4x8 tile; rolling 3-row window from LDS ----
    int tile_x = (tid & 31) * 4;
    int tile_y = (tid >> 5) * 8;
    const float NEG = -__builtin_inff();
    float4 A, B, C;
    if (tile_y > 0) A = *(const float4*)&lds[(tile_y - 1) * WW + tile_x];
    else            A = make_float4(NEG, NEG, NEG, NEG);
    B = *(const float4*)&lds[tile_y * WW + tile_x];

    int ccbase = bc * 32;
    uint64_t* cd = cand + (size_t)bc * CAP;
    int ibase = chan * HW + tile_y * WW + tile_x;

    #pragma unroll
    for (int j = 0; j < 8; ++j) {
        int yn = tile_y + j + 1;
        if (yn < HH) C = *(const float4*)&lds[yn * WW + tile_x];
        else         C = make_float4(NEG, NEG, NEG, NEG);

        float c0 = fmaxf(fmaxf(A.x, B.x), C.x);
        float c1 = fmaxf(fmaxf(A.y, B.y), C.y);
        float c2 = fmaxf(fmaxf(A.z, B.z), C.z);
        float c3 = fmaxf(fmaxf(A.w, B.w), C.w);
        float cl = __shfl_up(c3, 1);     // lane x0==0 masked below
        float cr = __shfl_down(c0, 1);   // lane x0==124 masked below
        if (tile_x == 0)      cl = NEG;
        if (tile_x == WW - 4) cr = NEG;
        float w0 = fmaxf(fmaxf(cl, c0), c1);
        float w1 = fmaxf(fmaxf(c0, c1), c2);
        float w2 = fmaxf(fmaxf(c1, c2), c3);
        float w3 = fmaxf(fmaxf(c2, c3), cr);

        // emission: P(taken) ~ 2e-4 per px -> exec-masked skip almost always
        #define EMIT(Wm, V, P) \
            if ((Wm) == (V) && (V) >= VTHR) { \
                uint32_t bt = __float_as_uint(sigmoidf(V)); \
                int pos = atomicAdd(&ccnt[ccbase], 1); \
                if (pos < CAP) \
                    cd[pos] = ((uint64_t)bt << 32) | \
                              (uint32_t)(~(uint32_t)(ibase + j * WW + (P))); \
            }
        EMIT(w0, B.x, 0)
        EMIT(w1, B.y, 1)
        EMIT(w2, B.z, 2)
        EMIT(w3, B.w, 3)
        #undef EMIT
        A = B; B = C;
    }
}

// on-the-fly key for the fallback (never expected on this input)
__device__ uint64_t key_at(const float* __restrict__ hb, int i) {
    float v = hb[i];
    int rem = i & (HW - 1);
    int y = rem >> 7, x = rem & (WW - 1);
    bool mx = true;
    if (y > 0) {
        if (x > 0      && hb[i - WW - 1] > v) mx = false;
        if (              hb[i - WW    ] > v) mx = false;
        if (x < WW - 1 && hb[i - WW + 1] > v) mx = false;
    }
    if (x > 0      && hb[i - 1] > v) mx = false;
    if (x < WW - 1 && hb[i + 1] > v) mx = false;
    if (y < HH - 1) {
        if (x > 0      && hb[i + WW - 1] > v) mx = false;
        if (              hb[i + WW    ] > v) mx = false;
        if (x < WW - 1 && hb[i + WW + 1] > v) mx = false;
    }
    if (!mx) return 0;
    return ((uint64_t)__float_as_uint(sigmoidf(v)) << 32) | (uint32_t)(~(uint32_t)i);
}

__device__ __forceinline__ bool fast_ok(const int* ccnt, int bc) {
    int n = ccnt[bc * 32];
    return (n >= KTOP) && (n <= CAP);
}

// ---- fallback kernel A: LDS histogram of all survivors (early-exits) ----
__global__ void __launch_bounds__(256) fb_hist(
        const int* __restrict__ ccnt,
        const float* __restrict__ tl, const float* __restrict__ br,
        const float* __restrict__ ct, uint32_t* __restrict__ hist) {
    int bc = blockIdx.y;
    if (fast_ok(ccnt, bc)) return;
    __shared__ uint32_t lh[NBINS];
    for (int i = threadIdx.x; i < NBINS; i += 256) lh[i] = 0;
    __syncthreads();
    int t = bc >> 3; int b = bc & 7;
    const float* heat = (t == 0) ? tl : (t == 1) ? br : ct;
    const float* hb = heat + (size_t)b * CHW;
    for (int i = blockIdx.x * 256 + threadIdx.x; i < CHW; i += 32 * 256) {
        uint64_t k = key_at(hb, i);
        if (k) atomicAdd(&lh[(uint32_t)(k >> 51)], 1u);
    }
    __syncthreads();
    uint32_t* gh = hist + (size_t)bc * NBINS;
    for (int i = threadIdx.x; i < NBINS; i += 256) {
        uint32_t c = lh[i];
        if (c) atomicAdd(&gh[i], c);
    }
}

// ---- fallback kernel B: threshold (early-exits) ----
__global__ void __launch_bounds__(256) fb_thresh(
        const int* __restrict__ ccnt, const uint32_t* __restrict__ hist,
        int* __restrict__ thr) {
    int bc = blockIdx.x;
    if (fast_ok(ccnt, bc)) return;
    __shared__ uint32_t csum[256];
    const uint32_t* h = hist + (size_t)bc * NBINS;
    int tid = threadIdx.x;
    uint32_t bins[16];
    #pragma unroll
    for (int i = 0; i < 16; ++i) bins[i] = h[tid * 16 + i];
    if (tid == 0) bins[0] = 0;
    uint32_t s = 0;
    #pragma unroll
    for (int i = 0; i < 16; ++i) s += bins[i];
    csum[tid] = s;
    __syncthreads();
    for (int step = 1; step < 256; step <<= 1) {
        uint32_t add = (tid + step < 256) ? csum[tid + step] : 0;
        __syncthreads();
        csum[tid] += add;
        __syncthreads();
    }
    uint32_t inc = csum[tid];
    uint32_t above = (tid + 1 < 256) ? csum[tid + 1] : 0;
    if (tid == 0 && inc < KTOP) thr[bc] = 1;
    if (above < KTOP && inc >= KTOP) {
        uint32_t cum = above;
        int T = 1;
        #pragma unroll
        for (int i = 15; i >= 0; --i) {
            cum += bins[i];
            if (cum >= KTOP) { T = tid * 16 + i; break; }
        }
        thr[bc] = T;
    }
}

// ---- fallback kernel C: collect survivors >= T into cand (early-exits) ----
__global__ void __launch_bounds__(256) fb_collect(
        const int* __restrict__ ccnt, const int* __restrict__ thr,
        const float* __restrict__ tl, const float* __restrict__ br,
        const float* __restrict__ ct,
        uint64_t* __restrict__ cand, int* __restrict__ ccnt2) {
    int bc = blockIdx.y;
    if (fast_ok(ccnt, bc)) return;
    int t = bc >> 3; int b = bc & 7;
    const float* heat = (t == 0) ? tl : (t == 1) ? br : ct;
    const float* hb = heat + (size_t)b * CHW;
    int T = thr[bc];
    for (int i = blockIdx.x * 256 + threadIdx.x; i < CHW; i += 32 * 256) {
        uint64_t k = key_at(hb, i);
        if (k && (int)(uint32_t)(k >> 51) >= T) {
            int pc = atomicAdd(&ccnt2[bc * 32], 1);
            if (pc < CAP) cand[(size_t)bc * CAP + pc] = k;
        }
    }
}

// descending bitonic sort of N u64 keys in LDS
template <int N>
__device__ void bitonic_desc(uint64_t* k) {
    for (int kk = 2; kk <= N; kk <<= 1) {
        for (int j = kk >> 1; j > 0; j >>= 1) {
            __syncthreads();
            for (int i = threadIdx.x; i < N; i += blockDim.x) {
                int l = i ^ j;
                if (l > i) {
                    uint64_t a = k[i], b = k[l];
                    bool up = ((i & kk) == 0);
                    if (up ? (a < b) : (a > b)) { k[i] = b; k[l] = a; }
                }
            }
        }
    }
    __syncthreads();
}

// ---- kernel 2: per (tensor,batch) sort candidates, emit top-100 ----
__global__ void __launch_bounds__(1024) k_select(
        const uint64_t* __restrict__ cand, const int* __restrict__ ccnt,
        const int* __restrict__ ccnt2,
        const float* __restrict__ tl_tag, const float* __restrict__ br_tag,
        const float* __restrict__ tl_regr, const float* __restrict__ br_regr,
        const float* __restrict__ ct_regr,
        float* __restrict__ cs, float* __restrict__ cx, float* __restrict__ cy,
        float* __restrict__ ce, int* __restrict__ ccls) {
    __shared__ uint64_t keys[CAP];
    int bc = blockIdx.x; int t = bc >> 3; int b = bc & 7;
    int nf = ccnt[bc * 32];
    bool ok = (nf >= KTOP) && (nf <= CAP);
    int n = ok ? nf : ccnt2[bc * 32];
    if (n > CAP) n = CAP;
    if (n <= 512) {
        for (int i = threadIdx.x; i < 512; i += 1024)
            keys[i] = (i < n) ? cand[(size_t)bc * CAP + i] : 0ull;
        bitonic_desc<512>(keys);
    } else if (n <= 2048) {
        for (int i = threadIdx.x; i < 2048; i += 1024)
            keys[i] = (i < n) ? cand[(size_t)bc * CAP + i] : 0ull;
        bitonic_desc<2048>(keys);
    } else {
        for (int i = threadIdx.x; i < CAP; i += 1024)
            keys[i] = (i < n) ? cand[(size_t)bc * CAP + i] : 0ull;
        bitonic_desc<CAP>(keys);
    }
    if (threadIdx.x < KTOP) {
        uint64_t key = keys[threadIdx.x];
        float s = __uint_as_float((uint32_t)(key >> 32));
        uint32_t idx = ~(uint32_t)key;
        int cls = (int)(idx >> 14);
        int rem = (int)(idx & (HW - 1));
        int y = rem >> 7, x = rem & (WW - 1);
        const float* regr = (t == 0) ? tl_regr : (t == 1) ? br_regr : ct_regr;
        float o0 = regr[((size_t)b * 2 + 0) * HW + rem];
        float o1 = regr[((size_t)b * 2 + 1) * HW + rem];
        float emb = 0.f;
        if (t == 0) emb = tl_tag[(size_t)b * HW + rem];
        else if (t == 1) emb = br_tag[(size_t)b * HW + rem];
        int o = bc * KTOP + threadIdx.x;
        cs[o] = s;
        cx[o] = (float)x + o0;
        cy[o] = (float)y + o1;
        ce[o] = emb;
        ccls[o] = cls;
    }
}

// ---- kernel 3: fused pairwise scoring + final top-1000 + centers ----
__global__ void __launch_bounds__(1024) k_pairfinal(
        const float* __restrict__ cs, const float* __restrict__ cx,
        const float* __restrict__ cy, const float* __restrict__ ce,
        const int* __restrict__ ccls, float* __restrict__ out) {
    int b = blockIdx.x;
    __shared__ float ts[KTOP], tx[KTOP], ty[KTOP], te[KTOP];
    __shared__ int   tc[KTOP];
    __shared__ float bs_[KTOP], bx[KTOP], by[KTOP], be[KTOP];
    __shared__ int   bcl[KTOP];
    __shared__ uint64_t acc[ACAP];
    __shared__ int aidx[ACAP];
    __shared__ int acnt_s;
    int tid = threadIdx.x;
    if (tid == 0) acnt_s = 0;
    if (tid < KTOP) {
        int o = (0 * NB + b) * KTOP + tid;
        ts[tid] = cs[o]; tx[tid] = cx[o]; ty[tid] = cy[o]; te[tid] = ce[o]; tc[tid] = ccls[o];
    } else if (tid >= 512 && tid < 512 + KTOP) {
        int k = tid - 512;
        int o = (1 * NB + b) * KTOP + k;
        bs_[k] = cs[o]; bx[k] = cx[o]; by[k] = cy[o]; be[k] = ce[o]; bcl[k] = ccls[o];
    }
    __syncthreads();
    for (int p = tid; p < NPAIR; p += 1024) {
        int i = p / KTOP, j = p - i * KTOP;
        bool rej = (tc[i] != bcl[j])
                 | (fabsf(te[i] - be[j]) > 0.5f)
                 | (bx[j] < tx[i])
                 | (by[j] < ty[i]);
        if (!rej) {
            float sc = (ts[i] + bs_[j]) * 0.5f;
            int pos = atomicAdd(&acnt_s, 1);
            if (pos < ACAP)
                acc[pos] = ((uint64_t)__float_as_uint(sc) << 32) | (uint32_t)(~(uint32_t)p);
        }
    }
    __syncthreads();
    int m = acnt_s; if (m > ACAP) m = ACAP;
    if (m <= 256) {
        for (int i = tid; i < 256; i += 1024) if (i >= m) acc[i] = 0;
        bitonic_desc<256>(acc);
    } else {
        for (int i = tid; i < ACAP; i += 1024) if (i >= m) acc[i] = 0;
        bitonic_desc<ACAP>(acc);
    }
    for (int i = tid; i < m; i += 1024) aidx[i] = (int)(~(uint32_t)acc[i]);
    __syncthreads();
    for (int d = tid; d < NDET; d += 1024) {
        int p; float sc;
        if (d < m) {
            p = aidx[d];
            sc = __uint_as_float((uint32_t)(acc[d] >> 32));
        } else {
            // (d-m)-th flat pair-index NOT in accepted set, ascending (stable -1 ties)
            int r = d - m;
            int idx = r;
            for (;;) {
                int c = 0;
                for (int a = 0; a < m; ++a) c += (aidx[a] <= idx) ? 1 : 0;
                int ni = r + c;
                if (ni == idx) break;
                idx = ni;
            }
            p = idx; sc = -1.f;
        }
        int i = p / KTOP, j = p - i * KTOP;
        int ot = (0 * NB + b) * KTOP + i;
        int ob = (1 * NB + b) * KTOP + j;
        float* dr = out + ((size_t)b * NDET + d) * 8;
        dr[0] = cx[ot]; dr[1] = cy[ot]; dr[2] = cx[ob]; dr[3] = cy[ob];
        dr[4] = sc; dr[5] = cs[ot]; dr[6] = cs[ob]; dr[7] = (float)ccls[ot];
    }
    if (tid < KTOP) {
        int oc = (2 * NB + b) * KTOP + tid;
        float* cr = out + (size_t)NB * NDET * 8 + ((size_t)b * KTOP + tid) * 4;
        cr[0] = cx[oc]; cr[1] = cy[oc]; cr[2] = (float)ccls[oc]; cr[3] = cs[oc];
    }
}

extern "C" void kernel_launch(void* const* d_in, const int* in_sizes, int n_in,
                              void* d_out, int out_size, void* d_ws, size_t ws_size,
                              hipStream_t stream) {
    const float* tl_heat = (const float*)d_in[0];
    const float* br_heat = (const float*)d_in[1];
    const float* ct_heat = (const float*)d_in[2];
    const float* tl_tag  = (const float*)d_in[3];
    const float* br_tag  = (const float*)d_in[4];
    const float* tl_regr = (const float*)d_in[5];
    const float* br_regr = (const float*)d_in[6];
    const float* ct_regr = (const float*)d_in[7];

    if (ws_size < (size_t)WS_NEEDED) return;   // ~1.2 MB

    char* ws = (char*)d_ws;
    int*      ccnt  = (int*)(ws + OFF_CCNT);
    int*      ccnt2 = (int*)(ws + OFF_CCNT2);
    uint32_t* hist  = (uint32_t*)(ws + OFF_HIST);
    int*      thr   = (int*)(ws + OFF_THR);
    uint64_t* cand  = (uint64_t*)(ws + OFF_CAND);
    float*    cs    = (float*)(ws + OFF_CS);
    float*    cx    = (float*)(ws + OFF_CX);
    float*    cy    = (float*)(ws + OFF_CY);
    float*    ce    = (float*)(ws + OFF_CE);
    int*      ccls  = (int*)(ws + OFF_CCLS);

    hipMemsetAsync(ws, 0, ZERO_BYTES, stream);   // ccnt + ccnt2 + hist

    k_nms<<<24 * NC, 512, 0, stream>>>(tl_heat, br_heat, ct_heat, cand, ccnt);
    fb_hist<<<dim3(32, 24), 256, 0, stream>>>(ccnt, tl_heat, br_heat, ct_heat, hist);
    fb_thresh<<<24, 256, 0, stream>>>(ccnt, hist, thr);
    fb_collect<<<dim3(32, 24), 256, 0, stream>>>(ccnt, thr,
                                                 tl_heat, br_heat, ct_heat,
                                                 cand, ccnt2);
    k_select<<<24, 1024, 0, stream>>>(cand, ccnt, ccnt2, tl_tag, br_tag,
                                      tl_regr, br_regr, ct_regr,
                                      cs, cx, cy, ce, ccls);
    k_pairfinal<<<NB, 1024, 0, stream>>>(cs, cx, cy, ce, ccls, (float*)d_out);
}

// Round 19
// 65.265 us; speedup vs baseline: 1.4251x; 1.0432x over previous
//
#include <hip/hip_runtime.h>
#include <cstdint>

// Problem constants (B=8, C=80, H=W=128, K=100, kernel=3, num_dets=1000)
#define NB    8
#define NC    80
#define HH    128
#define WW    128
#define HW    16384
#define CHW   1310720
#define KTOP  100
#define NDET  1000
#define NPAIR 10000
#define CAP   4096
#define ACAP  2048
#define NBINS 4096        // fallback hist: 12-bit bins over sigmoid bits (>>19)
#define VTHR  3.5f        // fixed conservative raw threshold; exactness VERIFIED by count

// ---- workspace layout (bytes) ----
#define OFF_CCNT   0                         // int[24*32] fast-path counts (128B apart)
#define OFF_CCNT2  3072                      // int[24*32] fallback counts
#define OFF_HIST   6144                      // u32[24][4096] (fallback only)
#define ZERO_BYTES 399360                    // ccnt+ccnt2+hist
#define OFF_THR    399360                    // int[32]
#define OFF_CAND   399488                    // u64[24][4096]
#define OFF_CS     1185920                   // float[2400]
#define OFF_CX     1195520
#define OFF_CY     1205120
#define OFF_CE     1214720
#define OFF_CCLS   1224320                   // int[2400]
#define WS_NEEDED  1233920                   // ~1.2 MB

// branchless, bit-identical to jax.nn.sigmoid's two-branch form
__device__ __forceinline__ float sigmoidf(float x) {
    float e = expf(-fabsf(x));
    return (x >= 0.f ? 1.f : e) / (1.f + e);
}

// ---- kernel 1: quarter-channel-tile NMS (8 blocks/CU for stage/stencil overlap) ----
// Block = (bc, chan, quarter): 32 rows + 2 halo rows staged to 17.4KB LDS via
// register path (allows -inf edge substitution), one barrier, stencil from LDS,
// per-survivor atomic emission (v >= VTHR; exactness verified by count).
__global__ void __launch_bounds__(256) k_nms(
        const float* __restrict__ tl, const float* __restrict__ br,
        const float* __restrict__ ct,
        uint64_t* __restrict__ cand, int* __restrict__ ccnt) {
    __shared__ float lds[34 * WW];   // 17408 B

    int tid = threadIdx.x;
    int bid = blockIdx.x;
    int bc = bid >> 8;                    // bid / 256  (80 chans * 4 quarters wait: 320)
    // NOTE: 80*4=320 blocks per bc -> decode manually
    bc = bid / 320;
    int rem_b = bid - bc * 320;
    int chan = rem_b >> 2;
    int q = rem_b & 3;
    int t = bc >> 3; int b = bc & 7;
    const float* heat = (t == 0) ? tl : (t == 1) ? br : ct;
    const float* cb = heat + (size_t)b * CHW + (size_t)chan * HW;
    int ybase = q * 32;
    const float NEG = -__builtin_inff();

    // ---- stage: 34 rows (ybase-1 .. ybase+32), clamped addr, -inf for OOB ----
    for (int k = tid; k < 34 * 32; k += 256) {
        int r = k >> 5;
        int c4 = (k & 31) << 2;
        int gy = ybase - 1 + r;
        int gyc = min(max(gy, 0), HH - 1);
        float4 v = *(const float4*)(cb + gyc * WW + c4);
        if (gy < 0 || gy > HH - 1) v = make_float4(NEG, NEG, NEG, NEG);
        *(float4*)&lds[r * WW + c4] = v;
    }
    __syncthreads();

    // ---- stencil: thread owns 4x4 px; rolling 3-row window from LDS ----
    int rg = tid >> 5;                    // row-group 0..7 (4 rows each)
    int tile_x = (tid & 31) << 2;
    int lrow = 1 + rg * 4;                // lds row of first owned image row
    float4 A = *(const float4*)&lds[(lrow - 1) * WW + tile_x];
    float4 B = *(const float4*)&lds[lrow * WW + tile_x];
    int ccbase = bc * 32;
    uint64_t* cd = cand + (size_t)bc * CAP;
    int ibase = chan * HW + (ybase + rg * 4) * WW + tile_x;

    #pragma unroll
    for (int j = 0; j < 4; ++j) {
        float4 C = *(const float4*)&lds[(lrow + j + 1) * WW + tile_x];
        float c0 = fmaxf(fmaxf(A.x, B.x), C.x);
        float c1 = fmaxf(fmaxf(A.y, B.y), C.y);
        float c2 = fmaxf(fmaxf(A.z, B.z), C.z);
        float c3 = fmaxf(fmaxf(A.w, B.w), C.w);
        float cl = __shfl_up(c3, 1);      // cross-row pulls masked by tile_x tests
        float cr = __shfl_down(c0, 1);
        if (tile_x == 0)      cl = NEG;
        if (tile_x == WW - 4) cr = NEG;
        float w0 = fmaxf(fmaxf(cl, c0), c1);
        float w1 = fmaxf(fmaxf(c0, c1), c2);
        float w2 = fmaxf(fmaxf(c1, c2), c3);
        float w3 = fmaxf(fmaxf(c2, c3), cr);

        #define EMIT(Wm, V, P) \
            if ((Wm) == (V) && (V) >= VTHR) { \
                uint32_t bt = __float_as_uint(sigmoidf(V)); \
                int pos = atomicAdd(&ccnt[ccbase], 1); \
                if (pos < CAP) \
                    cd[pos] = ((uint64_t)bt << 32) | \
                              (uint32_t)(~(uint32_t)(ibase + j * WW + (P))); \
            }
        EMIT(w0, B.x, 0)
        EMIT(w1, B.y, 1)
        EMIT(w2, B.z, 2)
        EMIT(w3, B.w, 3)
        #undef EMIT
        A = B; B = C;
    }
}

// on-the-fly key for the fallback (never expected on this input)
__device__ uint64_t key_at(const float* __restrict__ hb, int i) {
    float v = hb[i];
    int rem = i & (HW - 1);
    int y = rem >> 7, x = rem & (WW - 1);
    bool mx = true;
    if (y > 0) {
        if (x > 0      && hb[i - WW - 1] > v) mx = false;
        if (              hb[i - WW    ] > v) mx = false;
        if (x < WW - 1 && hb[i - WW + 1] > v) mx = false;
    }
    if (x > 0      && hb[i - 1] > v) mx = false;
    if (x < WW - 1 && hb[i + 1] > v) mx = false;
    if (y < HH - 1) {
        if (x > 0      && hb[i + WW - 1] > v) mx = false;
        if (              hb[i + WW    ] > v) mx = false;
        if (x < WW - 1 && hb[i + WW + 1] > v) mx = false;
    }
    if (!mx) return 0;
    return ((uint64_t)__float_as_uint(sigmoidf(v)) << 32) | (uint32_t)(~(uint32_t)i);
}

__device__ __forceinline__ bool fast_ok(const int* ccnt, int bc) {
    int n = ccnt[bc * 32];
    return (n >= KTOP) && (n <= CAP);
}

// ---- fallback kernel A: LDS histogram of all survivors (early-exits) ----
__global__ void __launch_bounds__(256) fb_hist(
        const int* __restrict__ ccnt,
        const float* __restrict__ tl, const float* __restrict__ br,
        const float* __restrict__ ct, uint32_t* __restrict__ hist) {
    int bc = blockIdx.y;
    if (fast_ok(ccnt, bc)) return;
    __shared__ uint32_t lh[NBINS];
    for (int i = threadIdx.x; i < NBINS; i += 256) lh[i] = 0;
    __syncthreads();
    int t = bc >> 3; int b = bc & 7;
    const float* heat = (t == 0) ? tl : (t == 1) ? br : ct;
    const float* hb = heat + (size_t)b * CHW;
    for (int i = blockIdx.x * 256 + threadIdx.x; i < CHW; i += 32 * 256) {
        uint64_t k = key_at(hb, i);
        if (k) atomicAdd(&lh[(uint32_t)(k >> 51)], 1u);
    }
    __syncthreads();
    uint32_t* gh = hist + (size_t)bc * NBINS;
    for (int i = threadIdx.x; i < NBINS; i += 256) {
        uint32_t c = lh[i];
        if (c) atomicAdd(&gh[i], c);
    }
}

// ---- fallback kernel B: threshold (early-exits) ----
__global__ void __launch_bounds__(256) fb_thresh(
        const int* __restrict__ ccnt, const uint32_t* __restrict__ hist,
        int* __restrict__ thr) {
    int bc = blockIdx.x;
    if (fast_ok(ccnt, bc)) return;
    __shared__ uint32_t csum[256];
    const uint32_t* h = hist + (size_t)bc * NBINS;
    int tid = threadIdx.x;
    uint32_t bins[16];
    #pragma unroll
    for (int i = 0; i < 16; ++i) bins[i] = h[tid * 16 + i];
    if (tid == 0) bins[0] = 0;
    uint32_t s = 0;
    #pragma unroll
    for (int i = 0; i < 16; ++i) s += bins[i];
    csum[tid] = s;
    __syncthreads();
    for (int step = 1; step < 256; step <<= 1) {
        uint32_t add = (tid + step < 256) ? csum[tid + step] : 0;
        __syncthreads();
        csum[tid] += add;
        __syncthreads();
    }
    uint32_t inc = csum[tid];
    uint32_t above = (tid + 1 < 256) ? csum[tid + 1] : 0;
    if (tid == 0 && inc < KTOP) thr[bc] = 1;
    if (above < KTOP && inc >= KTOP) {
        uint32_t cum = above;
        int T = 1;
        #pragma unroll
        for (int i = 15; i >= 0; --i) {
            cum += bins[i];
            if (cum >= KTOP) { T = tid * 16 + i; break; }
        }
        thr[bc] = T;
    }
}

// ---- fallback kernel C: collect survivors >= T into cand (early-exits) ----
__global__ void __launch_bounds__(256) fb_collect(
        const int* __restrict__ ccnt, const int* __restrict__ thr,
        const float* __restrict__ tl, const float* __restrict__ br,
        const float* __restrict__ ct,
        uint64_t* __restrict__ cand, int* __restrict__ ccnt2) {
    int bc = blockIdx.y;
    if (fast_ok(ccnt, bc)) return;
    int t = bc >> 3; int b = bc & 7;
    const float* heat = (t == 0) ? tl : (t == 1) ? br : ct;
    const float* hb = heat + (size_t)b * CHW;
    int T = thr[bc];
    for (int i = blockIdx.x * 256 + threadIdx.x; i < CHW; i += 32 * 256) {
        uint64_t k = key_at(hb, i);
        if (k && (int)(uint32_t)(k >> 51) >= T) {
            int pc = atomicAdd(&ccnt2[bc * 32], 1);
            if (pc < CAP) cand[(size_t)bc * CAP + pc] = k;
        }
    }
}

// descending bitonic sort of N u64 keys in LDS
template <int N>
__device__ void bitonic_desc(uint64_t* k) {
    for (int kk = 2; kk <= N; kk <<= 1) {
        for (int j = kk >> 1; j > 0; j >>= 1) {
            __syncthreads();
            for (int i = threadIdx.x; i < N; i += blockDim.x) {
                int l = i ^ j;
                if (l > i) {
                    uint64_t a = k[i], b = k[l];
                    bool up = ((i & kk) == 0);
                    if (up ? (a < b) : (a > b)) { k[i] = b; k[l] = a; }
                }
            }
        }
    }
    __syncthreads();
}

// ---- kernel 2: per (tensor,batch) sort candidates, emit top-100 ----
__global__ void __launch_bounds__(1024) k_select(
        const uint64_t* __restrict__ cand, const int* __restrict__ ccnt,
        const int* __restrict__ ccnt2,
        const float* __restrict__ tl_tag, const float* __restrict__ br_tag,
        const float* __restrict__ tl_regr, const float* __restrict__ br_regr,
        const float* __restrict__ ct_regr,
        float* __restrict__ cs, float* __restrict__ cx, float* __restrict__ cy,
        float* __restrict__ ce, int* __restrict__ ccls) {
    __shared__ uint64_t keys[CAP];
    int bc = blockIdx.x; int t = bc >> 3; int b = bc & 7;
    int nf = ccnt[bc * 32];
    bool ok = (nf >= KTOP) && (nf <= CAP);
    int n = ok ? nf : ccnt2[bc * 32];
    if (n > CAP) n = CAP;
    if (n <= 512) {
        for (int i = threadIdx.x; i < 512; i += 1024)
            keys[i] = (i < n) ? cand[(size_t)bc * CAP + i] : 0ull;
        bitonic_desc<512>(keys);
    } else if (n <= 2048) {
        for (int i = threadIdx.x; i < 2048; i += 1024)
            keys[i] = (i < n) ? cand[(size_t)bc * CAP + i] : 0ull;
        bitonic_desc<2048>(keys);
    } else {
        for (int i = threadIdx.x; i < CAP; i += 1024)
            keys[i] = (i < n) ? cand[(size_t)bc * CAP + i] : 0ull;
        bitonic_desc<CAP>(keys);
    }
    if (threadIdx.x < KTOP) {
        uint64_t key = keys[threadIdx.x];
        float s = __uint_as_float((uint32_t)(key >> 32));
        uint32_t idx = ~(uint32_t)key;
        int cls = (int)(idx >> 14);
        int rem = (int)(idx & (HW - 1));
        int y = rem >> 7, x = rem & (WW - 1);
        const float* regr = (t == 0) ? tl_regr : (t == 1) ? br_regr : ct_regr;
        float o0 = regr[((size_t)b * 2 + 0) * HW + rem];
        float o1 = regr[((size_t)b * 2 + 1) * HW + rem];
        float emb = 0.f;
        if (t == 0) emb = tl_tag[(size_t)b * HW + rem];
        else if (t == 1) emb = br_tag[(size_t)b * HW + rem];
        int o = bc * KTOP + threadIdx.x;
        cs[o] = s;
        cx[o] = (float)x + o0;
        cy[o] = (float)y + o1;
        ce[o] = emb;
        ccls[o] = cls;
    }
}

// ---- kernel 3: fused pairwise scoring + final top-1000 + centers ----
__global__ void __launch_bounds__(1024) k_pairfinal(
        const float* __restrict__ cs, const float* __restrict__ cx,
        const float* __restrict__ cy, const float* __restrict__ ce,
        const int* __restrict__ ccls, float* __restrict__ out) {
    int b = blockIdx.x;
    __shared__ float ts[KTOP], tx[KTOP], ty[KTOP], te[KTOP];
    __shared__ int   tc[KTOP];
    __shared__ float bs_[KTOP], bx[KTOP], by[KTOP], be[KTOP];
    __shared__ int   bcl[KTOP];
    __shared__ uint64_t acc[ACAP];
    __shared__ int aidx[ACAP];
    __shared__ int acnt_s;
    int tid = threadIdx.x;
    if (tid == 0) acnt_s = 0;
    if (tid < KTOP) {
        int o = (0 * NB + b) * KTOP + tid;
        ts[tid] = cs[o]; tx[tid] = cx[o]; ty[tid] = cy[o]; te[tid] = ce[o]; tc[tid] = ccls[o];
    } else if (tid >= 512 && tid < 512 + KTOP) {
        int k = tid - 512;
        int o = (1 * NB + b) * KTOP + k;
        bs_[k] = cs[o]; bx[k] = cx[o]; by[k] = cy[o]; be[k] = ce[o]; bcl[k] = ccls[o];
    }
    __syncthreads();
    for (int p = tid; p < NPAIR; p += 1024) {
        int i = p / KTOP, j = p - i * KTOP;
        bool rej = (tc[i] != bcl[j])
                 | (fabsf(te[i] - be[j]) > 0.5f)
                 | (bx[j] < tx[i])
                 | (by[j] < ty[i]);
        if (!rej) {
            float sc = (ts[i] + bs_[j]) * 0.5f;
            int pos = atomicAdd(&acnt_s, 1);
            if (pos < ACAP)
                acc[pos] = ((uint64_t)__float_as_uint(sc) << 32) | (uint32_t)(~(uint32_t)p);
        }
    }
    __syncthreads();
    int m = acnt_s; if (m > ACAP) m = ACAP;
    if (m <= 256) {
        for (int i = tid; i < 256; i += 1024) if (i >= m) acc[i] = 0;
        bitonic_desc<256>(acc);
    } else {
        for (int i = tid; i < ACAP; i += 1024) if (i >= m) acc[i] = 0;
        bitonic_desc<ACAP>(acc);
    }
    for (int i = tid; i < m; i += 1024) aidx[i] = (int)(~(uint32_t)acc[i]);
    __syncthreads();
    for (int d = tid; d < NDET; d += 1024) {
        int p; float sc;
        if (d < m) {
            p = aidx[d];
            sc = __uint_as_float((uint32_t)(acc[d] >> 32));
        } else {
            // (d-m)-th flat pair-index NOT in accepted set, ascending (stable -1 ties)
            int r = d - m;
            int idx = r;
            for (;;) {
                int c = 0;
                for (int a = 0; a < m; ++a) c += (aidx[a] <= idx) ? 1 : 0;
                int ni = r + c;
                if (ni == idx) break;
                idx = ni;
            }
            p = idx; sc = -1.f;
        }
        int i = p / KTOP, j = p - i * KTOP;
        int ot = (0 * NB + b) * KTOP + i;
        int ob = (1 * NB + b) * KTOP + j;
        float* dr = out + ((size_t)b * NDET + d) * 8;
        dr[0] = cx[ot]; dr[1] = cy[ot]; dr[2] = cx[ob]; dr[3] = cy[ob];
        dr[4] = sc; dr[5] = cs[ot]; dr[6] = cs[ob]; dr[7] = (float)ccls[ot];
    }
    if (tid < KTOP) {
        int oc = (2 * NB + b) * KTOP + tid;
        float* cr = out + (size_t)NB * NDET * 8 + ((size_t)b * KTOP + tid) * 4;
        cr[0] = cx[oc]; cr[1] = cy[oc]; cr[2] = (float)ccls[oc]; cr[3] = cs[oc];
    }
}

extern "C" void kernel_launch(void* const* d_in, const int* in_sizes, int n_in,
                              void* d_out, int out_size, void* d_ws, size_t ws_size,
                              hipStream_t stream) {
    const float* tl_heat = (const float*)d_in[0];
    const float* br_heat = (const float*)d_in[1];
    const float* ct_heat = (const float*)d_in[2];
    const float* tl_tag  = (const float*)d_in[3];
    const float* br_tag  = (const float*)d_in[4];
    const float* tl_regr = (const float*)d_in[5];
    const float* br_regr = (const float*)d_in[6];
    const float* ct_regr = (const float*)d_in[7];

    if (ws_size < (size_t)WS_NEEDED) return;   // ~1.2 MB

    char* ws = (char*)d_ws;
    int*      ccnt  = (int*)(ws + OFF_CCNT);
    int*      ccnt2 = (int*)(ws + OFF_CCNT2);
    uint32_t* hist  = (uint32_t*)(ws + OFF_HIST);
    int*      thr   = (int*)(ws + OFF_THR);
    uint64_t* cand  = (uint64_t*)(ws + OFF_CAND);
    float*    cs    = (float*)(ws + OFF_CS);
    float*    cx    = (float*)(ws + OFF_CX);
    float*    cy    = (float*)(ws + OFF_CY);
    float*    ce    = (float*)(ws + OFF_CE);
    int*      ccls  = (int*)(ws + OFF_CCLS);

    hipMemsetAsync(ws, 0, ZERO_BYTES, stream);   // ccnt + ccnt2 + hist

    k_nms<<<24 * NC * 4, 256, 0, stream>>>(tl_heat, br_heat, ct_heat, cand, ccnt);
    fb_hist<<<dim3(32, 24), 256, 0, stream>>>(ccnt, tl_heat, br_heat, ct_heat, hist);
    fb_thresh<<<24, 256, 0, stream>>>(ccnt, hist, thr);
    fb_collect<<<dim3(32, 24), 256, 0, stream>>>(ccnt, thr,
                                                 tl_heat, br_heat, ct_heat,
                                                 cand, ccnt2);
    k_select<<<24, 1024, 0, stream>>>(cand, ccnt, ccnt2, tl_tag, br_tag,
                                      tl_regr, br_regr, ct_regr,
                                      cs, cx, cy, ce, ccls);
    k_pairfinal<<<NB, 1024, 0, stream>>>(cs, cx, cy, ce, ccls, (float*)d_out);
}

// Round 21
// 63.408 us; speedup vs baseline: 1.4668x; 1.0293x over previous
//
#include <hip/hip_runtime.h>
#include <cstdint>

// Problem constants (B=8, C=80, H=W=128, K=100, kernel=3, num_dets=1000)
#define NB    8
#define NC    80
#define HH    128
#define WW    128
#define HW    16384
#define CHW   1310720
#define KTOP  100
#define NDET  1000
#define NPAIR 10000
#define CAP   4096
#define ACAP  2048
#define NBINS 4096        // fallback hist: 12-bit bins over sigmoid bits (>>19)
#define VTHR  3.5f        // fixed conservative raw threshold; exactness VERIFIED by count

// ---- workspace layout (bytes) ----
#define OFF_CCNT   0                         // int[24*32] fast-path counts (128B apart)
#define OFF_CCNT2  3072                      // int[24*32] fallback counts
#define OFF_HIST   6144                      // u32[24][4096] (fallback only)
#define ZERO_BYTES 399360                    // ccnt+ccnt2+hist
#define OFF_THR    399360                    // int[32]
#define OFF_CAND   399488                    // u64[24][4096]
#define OFF_CS     1185920                   // float[2400]
#define OFF_CX     1195520
#define OFF_CY     1205120
#define OFF_CE     1214720
#define OFF_CCLS   1224320                   // int[2400]
#define WS_NEEDED  1233920                   // ~1.2 MB

// branchless, bit-identical to jax.nn.sigmoid's two-branch form
__device__ __forceinline__ float sigmoidf(float x) {
    float e = expf(-fabsf(x));
    return (x >= 0.f ? 1.f : e) / (1.f + e);
}

// ---- kernel 1: quarter-channel-tile NMS, register staging with batched loads ----
// Block = (bc, chan, quarter): 34 rows -> 17.4KB LDS. All 4(+1) independent
// float4 loads issued back-to-back (pinned) BEFORE any store: 4-5 requests in
// flight per thread vs R19's ~2 (R19's VGPR=16 serialized the load->store pairs).
// Then -inf OOB substitution + LDS stores + one barrier + stencil. (R20's async
// global_load_lds variant was nondeterministic across replays -> reverted.)
__global__ void __launch_bounds__(256) k_nms(
        const float* __restrict__ tl, const float* __restrict__ br,
        const float* __restrict__ ct,
        uint64_t* __restrict__ cand, int* __restrict__ ccnt) {
    __shared__ float lds[34 * WW];   // 17408 B

    int tid = threadIdx.x;
    int bid = blockIdx.x;
    int bc = bid / 320;                  // 80 chans * 4 quarters per bc
    int rem_b = bid - bc * 320;
    int chan = rem_b >> 2;
    int q = rem_b & 3;
    int t = bc >> 3; int b = bc & 7;
    const float* heat = (t == 0) ? tl : (t == 1) ? br : ct;
    const float* cb = heat + (size_t)b * CHW + (size_t)chan * HW;
    int ybase = q * 32;
    const float NEG = -__builtin_inff();

    // ---- stage: 34 rows x 32 float4 = 1088 elems; 4 guaranteed + 1 cond load ----
    // element k: r = k>>5 (tile row), c4 = (k&31)*4 (col); global row clamped.
    #define GADDR(K, GY) ({ int r_ = (K) >> 5; (GY) = ybase - 1 + r_; \
                            int gyc_ = min(max((GY), 0), HH - 1); \
                            cb + gyc_ * WW + (((K) & 31) << 2); })
    int gy0, gy1, gy2, gy3, gy4 = 0;
    const float* a0 = GADDR(tid,        gy0);
    const float* a1 = GADDR(tid + 256,  gy1);
    const float* a2 = GADDR(tid + 512,  gy2);
    const float* a3 = GADDR(tid + 768,  gy3);
    float4 v0 = *(const float4*)a0;
    float4 v1 = *(const float4*)a1;
    float4 v2 = *(const float4*)a2;
    float4 v3 = *(const float4*)a3;
    float4 v4 = make_float4(0.f, 0.f, 0.f, 0.f);
    if (tid < 64) { const float* a4 = GADDR(tid + 1024, gy4); v4 = *(const float4*)a4; }
    #undef GADDR
    #define PIN(v) asm volatile("" : "+v"(v.x), "+v"(v.y), "+v"(v.z), "+v"(v.w))
    PIN(v0); PIN(v1); PIN(v2); PIN(v3); PIN(v4);
    #undef PIN

    #define STORE(K, V, GY) { \
        float4 vv = (V); \
        if ((GY) < 0 || (GY) > HH - 1) vv = make_float4(NEG, NEG, NEG, NEG); \
        *(float4*)&lds[(((K) >> 5) * WW) + (((K) & 31) << 2)] = vv; }
    STORE(tid,        v0, gy0)
    STORE(tid + 256,  v1, gy1)
    STORE(tid + 512,  v2, gy2)
    STORE(tid + 768,  v3, gy3)
    if (tid < 64) STORE(tid + 1024, v4, gy4)
    #undef STORE
    __syncthreads();

    // ---- stencil: thread owns 4x4 px; rolling 3-row window from LDS ----
    int rg = tid >> 5;                    // row-group 0..7 (4 rows each)
    int tile_x = (tid & 31) << 2;
    int lrow = 1 + rg * 4;
    float4 A = *(const float4*)&lds[(lrow - 1) * WW + tile_x];
    float4 B = *(const float4*)&lds[lrow * WW + tile_x];
    int ccbase = bc * 32;
    uint64_t* cd = cand + (size_t)bc * CAP;
    int ibase = chan * HW + (ybase + rg * 4) * WW + tile_x;

    #pragma unroll
    for (int j = 0; j < 4; ++j) {
        float4 C = *(const float4*)&lds[(lrow + j + 1) * WW + tile_x];
        float c0 = fmaxf(fmaxf(A.x, B.x), C.x);
        float c1 = fmaxf(fmaxf(A.y, B.y), C.y);
        float c2 = fmaxf(fmaxf(A.z, B.z), C.z);
        float c3 = fmaxf(fmaxf(A.w, B.w), C.w);
        float cl = __shfl_up(c3, 1);      // cross-row pulls masked by tile_x tests
        float cr = __shfl_down(c0, 1);
        if (tile_x == 0)      cl = NEG;
        if (tile_x == WW - 4) cr = NEG;
        float w0 = fmaxf(fmaxf(cl, c0), c1);
        float w1 = fmaxf(fmaxf(c0, c1), c2);
        float w2 = fmaxf(fmaxf(c1, c2), c3);
        float w3 = fmaxf(fmaxf(c2, c3), cr);

        #define EMIT(Wm, V, P) \
            if ((Wm) == (V) && (V) >= VTHR) { \
                uint32_t bt = __float_as_uint(sigmoidf(V)); \
                int pos = atomicAdd(&ccnt[ccbase], 1); \
                if (pos < CAP) \
                    cd[pos] = ((uint64_t)bt << 32) | \
                              (uint32_t)(~(uint32_t)(ibase + j * WW + (P))); \
            }
        EMIT(w0, B.x, 0)
        EMIT(w1, B.y, 1)
        EMIT(w2, B.z, 2)
        EMIT(w3, B.w, 3)
        #undef EMIT
        A = B; B = C;
    }
}

// on-the-fly key for the fallback (never expected on this input)
__device__ uint64_t key_at(const float* __restrict__ hb, int i) {
    float v = hb[i];
    int rem = i & (HW - 1);
    int y = rem >> 7, x = rem & (WW - 1);
    bool mx = true;
    if (y > 0) {
        if (x > 0      && hb[i - WW - 1] > v) mx = false;
        if (              hb[i - WW    ] > v) mx = false;
        if (x < WW - 1 && hb[i - WW + 1] > v) mx = false;
    }
    if (x > 0      && hb[i - 1] > v) mx = false;
    if (x < WW - 1 && hb[i + 1] > v) mx = false;
    if (y < HH - 1) {
        if (x > 0      && hb[i + WW - 1] > v) mx = false;
        if (              hb[i + WW    ] > v) mx = false;
        if (x < WW - 1 && hb[i + WW + 1] > v) mx = false;
    }
    if (!mx) return 0;
    return ((uint64_t)__float_as_uint(sigmoidf(v)) << 32) | (uint32_t)(~(uint32_t)i);
}

__device__ __forceinline__ bool fast_ok(const int* ccnt, int bc) {
    int n = ccnt[bc * 32];
    return (n >= KTOP) && (n <= CAP);
}

// ---- fallback kernel A: LDS histogram of all survivors (early-exits) ----
__global__ void __launch_bounds__(256) fb_hist(
        const int* __restrict__ ccnt,
        const float* __restrict__ tl, const float* __restrict__ br,
        const float* __restrict__ ct, uint32_t* __restrict__ hist) {
    int bc = blockIdx.y;
    if (fast_ok(ccnt, bc)) return;
    __shared__ uint32_t lh[NBINS];
    for (int i = threadIdx.x; i < NBINS; i += 256) lh[i] = 0;
    __syncthreads();
    int t = bc >> 3; int b = bc & 7;
    const float* heat = (t == 0) ? tl : (t == 1) ? br : ct;
    const float* hb = heat + (size_t)b * CHW;
    for (int i = blockIdx.x * 256 + threadIdx.x; i < CHW; i += 32 * 256) {
        uint64_t k = key_at(hb, i);
        if (k) atomicAdd(&lh[(uint32_t)(k >> 51)], 1u);
    }
    __syncthreads();
    uint32_t* gh = hist + (size_t)bc * NBINS;
    for (int i = threadIdx.x; i < NBINS; i += 256) {
        uint32_t c = lh[i];
        if (c) atomicAdd(&gh[i], c);
    }
}

// ---- fallback kernel B: threshold (early-exits) ----
__global__ void __launch_bounds__(256) fb_thresh(
        const int* __restrict__ ccnt, const uint32_t* __restrict__ hist,
        int* __restrict__ thr) {
    int bc = blockIdx.x;
    if (fast_ok(ccnt, bc)) return;
    __shared__ uint32_t csum[256];
    const uint32_t* h = hist + (size_t)bc * NBINS;
    int tid = threadIdx.x;
    uint32_t bins[16];
    #pragma unroll
    for (int i = 0; i < 16; ++i) bins[i] = h[tid * 16 + i];
    if (tid == 0) bins[0] = 0;
    uint32_t s = 0;
    #pragma unroll
    for (int i = 0; i < 16; ++i) s += bins[i];
    csum[tid] = s;
    __syncthreads();
    for (int step = 1; step < 256; step <<= 1) {
        uint32_t add = (tid + step < 256) ? csum[tid + step] : 0;
        __syncthreads();
        csum[tid] += add;
        __syncthreads();
    }
    uint32_t inc = csum[tid];
    uint32_t above = (tid + 1 < 256) ? csum[tid + 1] : 0;
    if (tid == 0 && inc < KTOP) thr[bc] = 1;
    if (above < KTOP && inc >= KTOP) {
        uint32_t cum = above;
        int T = 1;
        #pragma unroll
        for (int i = 15; i >= 0; --i) {
            cum += bins[i];
            if (cum >= KTOP) { T = tid * 16 + i; break; }
        }
        thr[bc] = T;
    }
}

// ---- fallback kernel C: collect survivors >= T into cand (early-exits) ----
__global__ void __launch_bounds__(256) fb_collect(
        const int* __restrict__ ccnt, const int* __restrict__ thr,
        const float* __restrict__ tl, const float* __restrict__ br,
        const float* __restrict__ ct,
        uint64_t* __restrict__ cand, int* __restrict__ ccnt2) {
    int bc = blockIdx.y;
    if (fast_ok(ccnt, bc)) return;
    int t = bc >> 3; int b = bc & 7;
    const float* heat = (t == 0) ? tl : (t == 1) ? br : ct;
    const float* hb = heat + (size_t)b * CHW;
    int T = thr[bc];
    for (int i = blockIdx.x * 256 + threadIdx.x; i < CHW; i += 32 * 256) {
        uint64_t k = key_at(hb, i);
        if (k && (int)(uint32_t)(k >> 51) >= T) {
            int pc = atomicAdd(&ccnt2[bc * 32], 1);
            if (pc < CAP) cand[(size_t)bc * CAP + pc] = k;
        }
    }
}

// descending bitonic sort of N u64 keys in LDS
template <int N>
__device__ void bitonic_desc(uint64_t* k) {
    for (int kk = 2; kk <= N; kk <<= 1) {
        for (int j = kk >> 1; j > 0; j >>= 1) {
            __syncthreads();
            for (int i = threadIdx.x; i < N; i += blockDim.x) {
                int l = i ^ j;
                if (l > i) {
                    uint64_t a = k[i], b = k[l];
                    bool up = ((i & kk) == 0);
                    if (up ? (a < b) : (a > b)) { k[i] = b; k[l] = a; }
                }
            }
        }
    }
    __syncthreads();
}

// ---- kernel 2: per (tensor,batch) sort candidates, emit top-100 ----
__global__ void __launch_bounds__(1024) k_select(
        const uint64_t* __restrict__ cand, const int* __restrict__ ccnt,
        const int* __restrict__ ccnt2,
        const float* __restrict__ tl_tag, const float* __restrict__ br_tag,
        const float* __restrict__ tl_regr, const float* __restrict__ br_regr,
        const float* __restrict__ ct_regr,
        float* __restrict__ cs, float* __restrict__ cx, float* __restrict__ cy,
        float* __restrict__ ce, int* __restrict__ ccls) {
    __shared__ uint64_t keys[CAP];
    int bc = blockIdx.x; int t = bc >> 3; int b = bc & 7;
    int nf = ccnt[bc * 32];
    bool ok = (nf >= KTOP) && (nf <= CAP);
    int n = ok ? nf : ccnt2[bc * 32];
    if (n > CAP) n = CAP;
    if (n <= 512) {
        for (int i = threadIdx.x; i < 512; i += 1024)
            keys[i] = (i < n) ? cand[(size_t)bc * CAP + i] : 0ull;
        bitonic_desc<512>(keys);
    } else if (n <= 2048) {
        for (int i = threadIdx.x; i < 2048; i += 1024)
            keys[i] = (i < n) ? cand[(size_t)bc * CAP + i] : 0ull;
        bitonic_desc<2048>(keys);
    } else {
        for (int i = threadIdx.x; i < CAP; i += 1024)
            keys[i] = (i < n) ? cand[(size_t)bc * CAP + i] : 0ull;
        bitonic_desc<CAP>(keys);
    }
    if (threadIdx.x < KTOP) {
        uint64_t key = keys[threadIdx.x];
        float s = __uint_as_float((uint32_t)(key >> 32));
        uint32_t idx = ~(uint32_t)key;
        int cls = (int)(idx >> 14);
        int rem = (int)(idx & (HW - 1));
        int y = rem >> 7, x = rem & (WW - 1);
        const float* regr = (t == 0) ? tl_regr : (t == 1) ? br_regr : ct_regr;
        float o0 = regr[((size_t)b * 2 + 0) * HW + rem];
        float o1 = regr[((size_t)b * 2 + 1) * HW + rem];
        float emb = 0.f;
        if (t == 0) emb = tl_tag[(size_t)b * HW + rem];
        else if (t == 1) emb = br_tag[(size_t)b * HW + rem];
        int o = bc * KTOP + threadIdx.x;
        cs[o] = s;
        cx[o] = (float)x + o0;
        cy[o] = (float)y + o1;
        ce[o] = emb;
        ccls[o] = cls;
    }
}

// ---- kernel 3: fused pairwise scoring + final top-1000 + centers ----
__global__ void __launch_bounds__(1024) k_pairfinal(
        const float* __restrict__ cs, const float* __restrict__ cx,
        const float* __restrict__ cy, const float* __restrict__ ce,
        const int* __restrict__ ccls, float* __restrict__ out) {
    int b = blockIdx.x;
    __shared__ float ts[KTOP], tx[KTOP], ty[KTOP], te[KTOP];
    __shared__ int   tc[KTOP];
    __shared__ float bs_[KTOP], bx[KTOP], by[KTOP], be[KTOP];
    __shared__ int   bcl[KTOP];
    __shared__ uint64_t acc[ACAP];
    __shared__ int aidx[ACAP];
    __shared__ int acnt_s;
    int tid = threadIdx.x;
    if (tid == 0) acnt_s = 0;
    if (tid < KTOP) {
        int o = (0 * NB + b) * KTOP + tid;
        ts[tid] = cs[o]; tx[tid] = cx[o]; ty[tid] = cy[o]; te[tid] = ce[o]; tc[tid] = ccls[o];
    } else if (tid >= 512 && tid < 512 + KTOP) {
        int k = tid - 512;
        int o = (1 * NB + b) * KTOP + k;
        bs_[k] = cs[o]; bx[k] = cx[o]; by[k] = cy[o]; be[k] = ce[o]; bcl[k] = ccls[o];
    }
    __syncthreads();
    for (int p = tid; p < NPAIR; p += 1024) {
        int i = p / KTOP, j = p - i * KTOP;
        bool rej = (tc[i] != bcl[j])
                 | (fabsf(te[i] - be[j]) > 0.5f)
                 | (bx[j] < tx[i])
                 | (by[j] < ty[i]);
        if (!rej) {
            float sc = (ts[i] + bs_[j]) * 0.5f;
            int pos = atomicAdd(&acnt_s, 1);
            if (pos < ACAP)
                acc[pos] = ((uint64_t)__float_as_uint(sc) << 32) | (uint32_t)(~(uint32_t)p);
        }
    }
    __syncthreads();
    int m = acnt_s; if (m > ACAP) m = ACAP;
    if (m <= 256) {
        for (int i = tid; i < 256; i += 1024) if (i >= m) acc[i] = 0;
        bitonic_desc<256>(acc);
    } else {
        for (int i = tid; i < ACAP; i += 1024) if (i >= m) acc[i] = 0;
        bitonic_desc<ACAP>(acc);
    }
    for (int i = tid; i < m; i += 1024) aidx[i] = (int)(~(uint32_t)acc[i]);
    __syncthreads();
    for (int d = tid; d < NDET; d += 1024) {
        int p; float sc;
        if (d < m) {
            p = aidx[d];
            sc = __uint_as_float((uint32_t)(acc[d] >> 32));
        } else {
            // (d-m)-th flat pair-index NOT in accepted set, ascending (stable -1 ties)
            int r = d - m;
            int idx = r;
            for (;;) {
                int c = 0;
                for (int a = 0; a < m; ++a) c += (aidx[a] <= idx) ? 1 : 0;
                int ni = r + c;
                if (ni == idx) break;
                idx = ni;
            }
            p = idx; sc = -1.f;
        }
        int i = p / KTOP, j = p - i * KTOP;
        int ot = (0 * NB + b) * KTOP + i;
        int ob = (1 * NB + b) * KTOP + j;
        float* dr = out + ((size_t)b * NDET + d) * 8;
        dr[0] = cx[ot]; dr[1] = cy[ot]; dr[2] = cx[ob]; dr[3] = cy[ob];
        dr[4] = sc; dr[5] = cs[ot]; dr[6] = cs[ob]; dr[7] = (float)ccls[ot];
    }
    if (tid < KTOP) {
        int oc = (2 * NB + b) * KTOP + tid;
        float* cr = out + (size_t)NB * NDET * 8 + ((size_t)b * KTOP + tid) * 4;
        cr[0] = cx[oc]; cr[1] = cy[oc]; cr[2] = (float)ccls[oc]; cr[3] = cs[oc];
    }
}

extern "C" void kernel_launch(void* const* d_in, const int* in_sizes, int n_in,
                              void* d_out, int out_size, void* d_ws, size_t ws_size,
                              hipStream_t stream) {
    const float* tl_heat = (const float*)d_in[0];
    const float* br_heat = (const float*)d_in[1];
    const float* ct_heat = (const float*)d_in[2];
    const float* tl_tag  = (const float*)d_in[3];
    const float* br_tag  = (const float*)d_in[4];
    const float* tl_regr = (const float*)d_in[5];
    const float* br_regr = (const float*)d_in[6];
    const float* ct_regr = (const float*)d_in[7];

    if (ws_size < (size_t)WS_NEEDED) return;   // ~1.2 MB

    char* ws = (char*)d_ws;
    int*      ccnt  = (int*)(ws + OFF_CCNT);
    int*      ccnt2 = (int*)(ws + OFF_CCNT2);
    uint32_t* hist  = (uint32_t*)(ws + OFF_HIST);
    int*      thr   = (int*)(ws + OFF_THR);
    uint64_t* cand  = (uint64_t*)(ws + OFF_CAND);
    float*    cs    = (float*)(ws + OFF_CS);
    float*    cx    = (float*)(ws + OFF_CX);
    float*    cy    = (float*)(ws + OFF_CY);
    float*    ce    = (float*)(ws + OFF_CE);
    int*      ccls  = (int*)(ws + OFF_CCLS);

    hipMemsetAsync(ws, 0, ZERO_BYTES, stream);   // ccnt + ccnt2 + hist

    k_nms<<<24 * NC * 4, 256, 0, stream>>>(tl_heat, br_heat, ct_heat, cand, ccnt);
    fb_hist<<<dim3(32, 24), 256, 0, stream>>>(ccnt, tl_heat, br_heat, ct_heat, hist);
    fb_thresh<<<24, 256, 0, stream>>>(ccnt, hist, thr);
    fb_collect<<<dim3(32, 24), 256, 0, stream>>>(ccnt, thr,
                                                 tl_heat, br_heat, ct_heat,
                                                 cand, ccnt2);
    k_select<<<24, 1024, 0, stream>>>(cand, ccnt, ccnt2, tl_tag, br_tag,
                                      tl_regr, br_regr, ct_regr,
                                      cs, cx, cy, ce, ccls);
    k_pairfinal<<<NB, 1024, 0, stream>>>(cs, cx, cy, ce, ccls, (float*)d_out);
}

// Round 22
// 59.488 us; speedup vs baseline: 1.5635x; 1.0659x over previous
//
#include <hip/hip_runtime.h>
#include <cstdint>

// Problem constants (B=8, C=80, H=W=128, K=100, kernel=3, num_dets=1000)
#define NB    8
#define NC    80
#define HH    128
#define WW    128
#define HW    16384
#define CHW   1310720
#define KTOP  100
#define NDET  1000
#define NPAIR 10000
#define CAP   4096
#define ACAP  2048
#define NBINS 4096        // fallback hist: 12-bit bins over sigmoid bits (>>19)
#define VTHR  3.5f        // fixed conservative raw threshold; exactness VERIFIED by count

// ---- workspace layout (bytes) ----
#define OFF_CCNT   0                         // int[24*32] fast-path counts (128B apart)
#define OFF_CCNT2  3072                      // int[24*32] fallback counts
#define ZERO_BYTES 6144                      // ccnt + ccnt2 only
#define OFF_CAND   6144                      // u64[24][4096]
#define OFF_CS     792576                    // float[2400]
#define OFF_CX     802176
#define OFF_CY     811776
#define OFF_CE     821376
#define OFF_CCLS   830976                    // int[2400]
#define WS_NEEDED  840576                    // ~0.84 MB

// branchless, bit-identical to jax.nn.sigmoid's two-branch form
__device__ __forceinline__ float sigmoidf(float x) {
    float e = expf(-fabsf(x));
    return (x >= 0.f ? 1.f : e) / (1.f + e);
}

// ---- kernel 1: quarter-channel-tile NMS, register staging with batched loads ----
// (R21-proven: 43.4us, 12 structural variants all 43-58us -> treated as floor.)
__global__ void __launch_bounds__(256) k_nms(
        const float* __restrict__ tl, const float* __restrict__ br,
        const float* __restrict__ ct,
        uint64_t* __restrict__ cand, int* __restrict__ ccnt) {
    __shared__ float lds[34 * WW];   // 17408 B

    int tid = threadIdx.x;
    int bid = blockIdx.x;
    int bc = bid / 320;                  // 80 chans * 4 quarters per bc
    int rem_b = bid - bc * 320;
    int chan = rem_b >> 2;
    int q = rem_b & 3;
    int t = bc >> 3; int b = bc & 7;
    const float* heat = (t == 0) ? tl : (t == 1) ? br : ct;
    const float* cb = heat + (size_t)b * CHW + (size_t)chan * HW;
    int ybase = q * 32;
    const float NEG = -__builtin_inff();

    // stage: 34 rows x 32 float4 = 1088 elems; 4 guaranteed + 1 cond load
    #define GADDR(K, GY) ({ int r_ = (K) >> 5; (GY) = ybase - 1 + r_; \
                            int gyc_ = min(max((GY), 0), HH - 1); \
                            cb + gyc_ * WW + (((K) & 31) << 2); })
    int gy0, gy1, gy2, gy3, gy4 = 0;
    const float* a0 = GADDR(tid,        gy0);
    const float* a1 = GADDR(tid + 256,  gy1);
    const float* a2 = GADDR(tid + 512,  gy2);
    const float* a3 = GADDR(tid + 768,  gy3);
    float4 v0 = *(const float4*)a0;
    float4 v1 = *(const float4*)a1;
    float4 v2 = *(const float4*)a2;
    float4 v3 = *(const float4*)a3;
    float4 v4 = make_float4(0.f, 0.f, 0.f, 0.f);
    if (tid < 64) { const float* a4 = GADDR(tid + 1024, gy4); v4 = *(const float4*)a4; }
    #undef GADDR
    #define PIN(v) asm volatile("" : "+v"(v.x), "+v"(v.y), "+v"(v.z), "+v"(v.w))
    PIN(v0); PIN(v1); PIN(v2); PIN(v3); PIN(v4);
    #undef PIN

    #define STORE(K, V, GY) { \
        float4 vv = (V); \
        if ((GY) < 0 || (GY) > HH - 1) vv = make_float4(NEG, NEG, NEG, NEG); \
        *(float4*)&lds[(((K) >> 5) * WW) + (((K) & 31) << 2)] = vv; }
    STORE(tid,        v0, gy0)
    STORE(tid + 256,  v1, gy1)
    STORE(tid + 512,  v2, gy2)
    STORE(tid + 768,  v3, gy3)
    if (tid < 64) STORE(tid + 1024, v4, gy4)
    #undef STORE
    __syncthreads();

    // stencil: thread owns 4x4 px; rolling 3-row window from LDS
    int rg = tid >> 5;                    // row-group 0..7 (4 rows each)
    int tile_x = (tid & 31) << 2;
    int lrow = 1 + rg * 4;
    float4 A = *(const float4*)&lds[(lrow - 1) * WW + tile_x];
    float4 B = *(const float4*)&lds[lrow * WW + tile_x];
    int ccbase = bc * 32;
    uint64_t* cd = cand + (size_t)bc * CAP;
    int ibase = chan * HW + (ybase + rg * 4) * WW + tile_x;

    #pragma unroll
    for (int j = 0; j < 4; ++j) {
        float4 C = *(const float4*)&lds[(lrow + j + 1) * WW + tile_x];
        float c0 = fmaxf(fmaxf(A.x, B.x), C.x);
        float c1 = fmaxf(fmaxf(A.y, B.y), C.y);
        float c2 = fmaxf(fmaxf(A.z, B.z), C.z);
        float c3 = fmaxf(fmaxf(A.w, B.w), C.w);
        float cl = __shfl_up(c3, 1);      // cross-row pulls masked by tile_x tests
        float cr = __shfl_down(c0, 1);
        if (tile_x == 0)      cl = NEG;
        if (tile_x == WW - 4) cr = NEG;
        float w0 = fmaxf(fmaxf(cl, c0), c1);
        float w1 = fmaxf(fmaxf(c0, c1), c2);
        float w2 = fmaxf(fmaxf(c1, c2), c3);
        float w3 = fmaxf(fmaxf(c2, c3), cr);

        #define EMIT(Wm, V, P) \
            if ((Wm) == (V) && (V) >= VTHR) { \
                uint32_t bt = __float_as_uint(sigmoidf(V)); \
                int pos = atomicAdd(&ccnt[ccbase], 1); \
                if (pos < CAP) \
                    cd[pos] = ((uint64_t)bt << 32) | \
                              (uint32_t)(~(uint32_t)(ibase + j * WW + (P))); \
            }
        EMIT(w0, B.x, 0)
        EMIT(w1, B.y, 1)
        EMIT(w2, B.z, 2)
        EMIT(w3, B.w, 3)
        #undef EMIT
        A = B; B = C;
    }
}

// on-the-fly key for the fallback (never expected on this input)
__device__ uint64_t key_at(const float* __restrict__ hb, int i) {
    float v = hb[i];
    int rem = i & (HW - 1);
    int y = rem >> 7, x = rem & (WW - 1);
    bool mx = true;
    if (y > 0) {
        if (x > 0      && hb[i - WW - 1] > v) mx = false;
        if (              hb[i - WW    ] > v) mx = false;
        if (x < WW - 1 && hb[i - WW + 1] > v) mx = false;
    }
    if (x > 0      && hb[i - 1] > v) mx = false;
    if (x < WW - 1 && hb[i + 1] > v) mx = false;
    if (y < HH - 1) {
        if (x > 0      && hb[i + WW - 1] > v) mx = false;
        if (              hb[i + WW    ] > v) mx = false;
        if (x < WW - 1 && hb[i + WW + 1] > v) mx = false;
    }
    if (!mx) return 0;
    return ((uint64_t)__float_as_uint(sigmoidf(v)) << 32) | (uint32_t)(~(uint32_t)i);
}

__device__ __forceinline__ bool fast_ok(const int* ccnt, int bc) {
    int n = ccnt[bc * 32];
    return (n >= KTOP) && (n <= CAP);
}

// ---- fallback kernel: ALL phases (hist -> thresh -> collect) in ONE block/bc ----
// Early-exits in the common case (fixed-threshold count verified in range).
// Perf irrelevant: it exists only for exactness on pathological inputs.
__global__ void __launch_bounds__(1024) fb_all(
        const int* __restrict__ ccnt,
        const float* __restrict__ tl, const float* __restrict__ br,
        const float* __restrict__ ct,
        uint64_t* __restrict__ cand, int* __restrict__ ccnt2) {
    int bc = blockIdx.x;
    if (fast_ok(ccnt, bc)) return;
    __shared__ uint32_t lh[NBINS];      // 16 KB
    __shared__ uint32_t csum[1024];
    __shared__ int thr_s;
    int tid = threadIdx.x;
    int t = bc >> 3; int b = bc & 7;
    const float* heat = (t == 0) ? tl : (t == 1) ? br : ct;
    const float* hb = heat + (size_t)b * CHW;

    // phase 1: histogram of all NMS survivors (12-bit sigmoid bins)
    for (int i = tid; i < NBINS; i += 1024) lh[i] = 0;
    __syncthreads();
    for (int i = tid; i < CHW; i += 1024) {
        uint64_t k = key_at(hb, i);
        if (k) atomicAdd(&lh[(uint32_t)(k >> 51)], 1u);
    }
    __syncthreads();

    // phase 2: threshold = largest bin>=1 with suffix count >= K (bin 0 excluded)
    uint32_t bins[4];
    #pragma unroll
    for (int i = 0; i < 4; ++i) bins[i] = lh[tid * 4 + i];
    if (tid == 0) bins[0] = 0;
    uint32_t s = bins[0] + bins[1] + bins[2] + bins[3];
    csum[tid] = s;
    __syncthreads();
    for (int step = 1; step < 1024; step <<= 1) {
        uint32_t add = (tid + step < 1024) ? csum[tid + step] : 0;
        __syncthreads();
        csum[tid] += add;
        __syncthreads();
    }
    uint32_t inc = csum[tid];
    uint32_t above = (tid < 1023) ? csum[tid + 1] : 0;
    if (tid == 0 && (int)inc < KTOP) thr_s = 1;
    if ((int)above < KTOP && (int)inc >= KTOP) {
        uint32_t cum = above;
        int T = 1;
        #pragma unroll
        for (int i = 3; i >= 0; --i) {
            cum += bins[i];
            if ((int)cum >= KTOP) { T = tid * 4 + i; break; }
        }
        thr_s = T;
    }
    __syncthreads();
    int T = thr_s;

    // phase 3: collect survivors >= T into cand (overwrites fast-path slots)
    for (int i = tid; i < CHW; i += 1024) {
        uint64_t k = key_at(hb, i);
        if (k && (int)(uint32_t)(k >> 51) >= T) {
            int pc = atomicAdd(&ccnt2[bc * 32], 1);
            if (pc < CAP) cand[(size_t)bc * CAP + pc] = k;
        }
    }
}

// descending bitonic sort of N u64 keys in LDS
template <int N>
__device__ void bitonic_desc(uint64_t* k) {
    for (int kk = 2; kk <= N; kk <<= 1) {
        for (int j = kk >> 1; j > 0; j >>= 1) {
            __syncthreads();
            for (int i = threadIdx.x; i < N; i += blockDim.x) {
                int l = i ^ j;
                if (l > i) {
                    uint64_t a = k[i], b = k[l];
                    bool up = ((i & kk) == 0);
                    if (up ? (a < b) : (a > b)) { k[i] = b; k[l] = a; }
                }
            }
        }
    }
    __syncthreads();
}

// ---- kernel 2: per (tensor,batch) sort candidates, emit top-100 ----
__global__ void __launch_bounds__(1024) k_select(
        const uint64_t* __restrict__ cand, const int* __restrict__ ccnt,
        const int* __restrict__ ccnt2,
        const float* __restrict__ tl_tag, const float* __restrict__ br_tag,
        const float* __restrict__ tl_regr, const float* __restrict__ br_regr,
        const float* __restrict__ ct_regr,
        float* __restrict__ cs, float* __restrict__ cx, float* __restrict__ cy,
        float* __restrict__ ce, int* __restrict__ ccls) {
    __shared__ uint64_t keys[CAP];
    int bc = blockIdx.x; int t = bc >> 3; int b = bc & 7;
    int nf = ccnt[bc * 32];
    bool ok = (nf >= KTOP) && (nf <= CAP);
    int n = ok ? nf : ccnt2[bc * 32];
    if (n > CAP) n = CAP;
    if (n <= 512) {
        for (int i = threadIdx.x; i < 512; i += 1024)
            keys[i] = (i < n) ? cand[(size_t)bc * CAP + i] : 0ull;
        bitonic_desc<512>(keys);
    } else if (n <= 2048) {
        for (int i = threadIdx.x; i < 2048; i += 1024)
            keys[i] = (i < n) ? cand[(size_t)bc * CAP + i] : 0ull;
        bitonic_desc<2048>(keys);
    } else {
        for (int i = threadIdx.x; i < CAP; i += 1024)
            keys[i] = (i < n) ? cand[(size_t)bc * CAP + i] : 0ull;
        bitonic_desc<CAP>(keys);
    }
    if (threadIdx.x < KTOP) {
        uint64_t key = keys[threadIdx.x];
        float s = __uint_as_float((uint32_t)(key >> 32));
        uint32_t idx = ~(uint32_t)key;
        int cls = (int)(idx >> 14);
        int rem = (int)(idx & (HW - 1));
        int y = rem >> 7, x = rem & (WW - 1);
        const float* regr = (t == 0) ? tl_regr : (t == 1) ? br_regr : ct_regr;
        float o0 = regr[((size_t)b * 2 + 0) * HW + rem];
        float o1 = regr[((size_t)b * 2 + 1) * HW + rem];
        float emb = 0.f;
        if (t == 0) emb = tl_tag[(size_t)b * HW + rem];
        else if (t == 1) emb = br_tag[(size_t)b * HW + rem];
        int o = bc * KTOP + threadIdx.x;
        cs[o] = s;
        cx[o] = (float)x + o0;
        cy[o] = (float)y + o1;
        ce[o] = emb;
        ccls[o] = cls;
    }
}

// ---- kernel 3: fused pairwise scoring + final top-1000 + centers ----
__global__ void __launch_bounds__(1024) k_pairfinal(
        const float* __restrict__ cs, const float* __restrict__ cx,
        const float* __restrict__ cy, const float* __restrict__ ce,
        const int* __restrict__ ccls, float* __restrict__ out) {
    int b = blockIdx.x;
    __shared__ float ts[KTOP], tx[KTOP], ty[KTOP], te[KTOP];
    __shared__ int   tc[KTOP];
    __shared__ float bs_[KTOP], bx[KTOP], by[KTOP], be[KTOP];
    __shared__ int   bcl[KTOP];
    __shared__ uint64_t acc[ACAP];
    __shared__ int aidx[ACAP];
    __shared__ int acnt_s;
    int tid = threadIdx.x;
    if (tid == 0) acnt_s = 0;
    if (tid < KTOP) {
        int o = (0 * NB + b) * KTOP + tid;
        ts[tid] = cs[o]; tx[tid] = cx[o]; ty[tid] = cy[o]; te[tid] = ce[o]; tc[tid] = ccls[o];
    } else if (tid >= 512 && tid < 512 + KTOP) {
        int k = tid - 512;
        int o = (1 * NB + b) * KTOP + k;
        bs_[k] = cs[o]; bx[k] = cx[o]; by[k] = cy[o]; be[k] = ce[o]; bcl[k] = ccls[o];
    }
    __syncthreads();
    for (int p = tid; p < NPAIR; p += 1024) {
        int i = p / KTOP, j = p - i * KTOP;
        bool rej = (tc[i] != bcl[j])
                 | (fabsf(te[i] - be[j]) > 0.5f)
                 | (bx[j] < tx[i])
                 | (by[j] < ty[i]);
        if (!rej) {
            float sc = (ts[i] + bs_[j]) * 0.5f;
            int pos = atomicAdd(&acnt_s, 1);
            if (pos < ACAP)
                acc[pos] = ((uint64_t)__float_as_uint(sc) << 32) | (uint32_t)(~(uint32_t)p);
        }
    }
    __syncthreads();
    int m = acnt_s; if (m > ACAP) m = ACAP;
    if (m <= 256) {
        for (int i = tid; i < 256; i += 1024) if (i >= m) acc[i] = 0;
        bitonic_desc<256>(acc);
    } else {
        for (int i = tid; i < ACAP; i += 1024) if (i >= m) acc[i] = 0;
        bitonic_desc<ACAP>(acc);
    }
    for (int i = tid; i < m; i += 1024) aidx[i] = (int)(~(uint32_t)acc[i]);
    __syncthreads();
    for (int d = tid; d < NDET; d += 1024) {
        int p; float sc;
        if (d < m) {
            p = aidx[d];
            sc = __uint_as_float((uint32_t)(acc[d] >> 32));
        } else {
            // (d-m)-th flat pair-index NOT in accepted set, ascending (stable -1 ties)
            int r = d - m;
            int idx = r;
            for (;;) {
                int c = 0;
                for (int a = 0; a < m; ++a) c += (aidx[a] <= idx) ? 1 : 0;
                int ni = r + c;
                if (ni == idx) break;
                idx = ni;
            }
            p = idx; sc = -1.f;
        }
        int i = p / KTOP, j = p - i * KTOP;
        int ot = (0 * NB + b) * KTOP + i;
        int ob = (1 * NB + b) * KTOP + j;
        float* dr = out + ((size_t)b * NDET + d) * 8;
        dr[0] = cx[ot]; dr[1] = cy[ot]; dr[2] = cx[ob]; dr[3] = cy[ob];
        dr[4] = sc; dr[5] = cs[ot]; dr[6] = cs[ob]; dr[7] = (float)ccls[ot];
    }
    if (tid < KTOP) {
        int oc = (2 * NB + b) * KTOP + tid;
        float* cr = out + (size_t)NB * NDET * 8 + ((size_t)b * KTOP + tid) * 4;
        cr[0] = cx[oc]; cr[1] = cy[oc]; cr[2] = (float)ccls[oc]; cr[3] = cs[oc];
    }
}

extern "C" void kernel_launch(void* const* d_in, const int* in_sizes, int n_in,
                              void* d_out, int out_size, void* d_ws, size_t ws_size,
                              hipStream_t stream) {
    const float* tl_heat = (const float*)d_in[0];
    const float* br_heat = (const float*)d_in[1];
    const float* ct_heat = (const float*)d_in[2];
    const float* tl_tag  = (const float*)d_in[3];
    const float* br_tag  = (const float*)d_in[4];
    const float* tl_regr = (const float*)d_in[5];
    const float* br_regr = (const float*)d_in[6];
    const float* ct_regr = (const float*)d_in[7];

    if (ws_size < (size_t)WS_NEEDED) return;   // ~0.84 MB

    char* ws = (char*)d_ws;
    int*      ccnt  = (int*)(ws + OFF_CCNT);
    int*      ccnt2 = (int*)(ws + OFF_CCNT2);
    uint64_t* cand  = (uint64_t*)(ws + OFF_CAND);
    float*    cs    = (float*)(ws + OFF_CS);
    float*    cx    = (float*)(ws + OFF_CX);
    float*    cy    = (float*)(ws + OFF_CY);
    float*    ce    = (float*)(ws + OFF_CE);
    int*      ccls  = (int*)(ws + OFF_CCLS);

    hipMemsetAsync(ws, 0, ZERO_BYTES, stream);   // ccnt + ccnt2 (6 KB)

    k_nms<<<24 * NC * 4, 256, 0, stream>>>(tl_heat, br_heat, ct_heat, cand, ccnt);
    fb_all<<<24, 1024, 0, stream>>>(ccnt, tl_heat, br_heat, ct_heat, cand, ccnt2);
    k_select<<<24, 1024, 0, stream>>>(cand, ccnt, ccnt2, tl_tag, br_tag,
                                      tl_regr, br_regr, ct_regr,
                                      cs, cx, cy, ce, ccls);
    k_pairfinal<<<NB, 1024, 0, stream>>>(cs, cx, cy, ce, ccls, (float*)d_out);
}

// Round 23
// 58.252 us; speedup vs baseline: 1.5966x; 1.0212x over previous
//
#include <hip/hip_runtime.h>
#include <cstdint>

// Problem constants (B=8, C=80, H=W=128, K=100, kernel=3, num_dets=1000)
#define NB    8
#define NC    80
#define HH    128
#define WW    128
#define HW    16384
#define CHW   1310720
#define KTOP  100
#define NDET  1000
#define NPAIR 10000
#define CAP   4096
#define ACAP  2048
#define NBINS 4096        // fallback hist: 12-bit bins over sigmoid bits (>>19)
#define VTHR  3.5f        // fixed conservative raw threshold; exactness VERIFIED by count

// ---- workspace layout (bytes) ----
#define OFF_CCNT   0                         // int[24*32] fast-path counts (128B apart)
#define ZERO_BYTES 3072                      // ccnt only
#define OFF_CAND   3072                      // u64[24][4096]
#define OFF_CS     789504                    // float[2400]
#define OFF_CX     799104
#define OFF_CY     808704
#define OFF_CE     818304
#define OFF_CCLS   827904                    // int[2400]
#define WS_NEEDED  837504                    // ~0.84 MB

// branchless, bit-identical to jax.nn.sigmoid's two-branch form
__device__ __forceinline__ float sigmoidf(float x) {
    float e = expf(-fabsf(x));
    return (x >= 0.f ? 1.f : e) / (1.f + e);
}

// ---- kernel 1: quarter-channel-tile NMS, register staging with batched loads ----
// (R21-proven floor: 43-46us across 13 structural variants; warm==cold ->
// latency-structured, not BW/VALU bound.)
__global__ void __launch_bounds__(256) k_nms(
        const float* __restrict__ tl, const float* __restrict__ br,
        const float* __restrict__ ct,
        uint64_t* __restrict__ cand, int* __restrict__ ccnt) {
    __shared__ float lds[34 * WW];   // 17408 B

    int tid = threadIdx.x;
    int bid = blockIdx.x;
    int bc = bid / 320;                  // 80 chans * 4 quarters per bc
    int rem_b = bid - bc * 320;
    int chan = rem_b >> 2;
    int q = rem_b & 3;
    int t = bc >> 3; int b = bc & 7;
    const float* heat = (t == 0) ? tl : (t == 1) ? br : ct;
    const float* cb = heat + (size_t)b * CHW + (size_t)chan * HW;
    int ybase = q * 32;
    const float NEG = -__builtin_inff();

    // stage: 34 rows x 32 float4 = 1088 elems; 4 guaranteed + 1 cond load
    #define GADDR(K, GY) ({ int r_ = (K) >> 5; (GY) = ybase - 1 + r_; \
                            int gyc_ = min(max((GY), 0), HH - 1); \
                            cb + gyc_ * WW + (((K) & 31) << 2); })
    int gy0, gy1, gy2, gy3, gy4 = 0;
    const float* a0 = GADDR(tid,        gy0);
    const float* a1 = GADDR(tid + 256,  gy1);
    const float* a2 = GADDR(tid + 512,  gy2);
    const float* a3 = GADDR(tid + 768,  gy3);
    float4 v0 = *(const float4*)a0;
    float4 v1 = *(const float4*)a1;
    float4 v2 = *(const float4*)a2;
    float4 v3 = *(const float4*)a3;
    float4 v4 = make_float4(0.f, 0.f, 0.f, 0.f);
    if (tid < 64) { const float* a4 = GADDR(tid + 1024, gy4); v4 = *(const float4*)a4; }
    #undef GADDR
    #define PIN(v) asm volatile("" : "+v"(v.x), "+v"(v.y), "+v"(v.z), "+v"(v.w))
    PIN(v0); PIN(v1); PIN(v2); PIN(v3); PIN(v4);
    #undef PIN

    #define STORE(K, V, GY) { \
        float4 vv = (V); \
        if ((GY) < 0 || (GY) > HH - 1) vv = make_float4(NEG, NEG, NEG, NEG); \
        *(float4*)&lds[(((K) >> 5) * WW) + (((K) & 31) << 2)] = vv; }
    STORE(tid,        v0, gy0)
    STORE(tid + 256,  v1, gy1)
    STORE(tid + 512,  v2, gy2)
    STORE(tid + 768,  v3, gy3)
    if (tid < 64) STORE(tid + 1024, v4, gy4)
    #undef STORE
    __syncthreads();

    // stencil: thread owns 4x4 px; rolling 3-row window from LDS
    int rg = tid >> 5;                    // row-group 0..7 (4 rows each)
    int tile_x = (tid & 31) << 2;
    int lrow = 1 + rg * 4;
    float4 A = *(const float4*)&lds[(lrow - 1) * WW + tile_x];
    float4 B = *(const float4*)&lds[lrow * WW + tile_x];
    int ccbase = bc * 32;
    uint64_t* cd = cand + (size_t)bc * CAP;
    int ibase = chan * HW + (ybase + rg * 4) * WW + tile_x;

    #pragma unroll
    for (int j = 0; j < 4; ++j) {
        float4 C = *(const float4*)&lds[(lrow + j + 1) * WW + tile_x];
        float c0 = fmaxf(fmaxf(A.x, B.x), C.x);
        float c1 = fmaxf(fmaxf(A.y, B.y), C.y);
        float c2 = fmaxf(fmaxf(A.z, B.z), C.z);
        float c3 = fmaxf(fmaxf(A.w, B.w), C.w);
        float cl = __shfl_up(c3, 1);      // cross-row pulls masked by tile_x tests
        float cr = __shfl_down(c0, 1);
        if (tile_x == 0)      cl = NEG;
        if (tile_x == WW - 4) cr = NEG;
        float w0 = fmaxf(fmaxf(cl, c0), c1);
        float w1 = fmaxf(fmaxf(c0, c1), c2);
        float w2 = fmaxf(fmaxf(c1, c2), c3);
        float w3 = fmaxf(fmaxf(c2, c3), cr);

        #define EMIT(Wm, V, P) \
            if ((Wm) == (V) && (V) >= VTHR) { \
                uint32_t bt = __float_as_uint(sigmoidf(V)); \
                int pos = atomicAdd(&ccnt[ccbase], 1); \
                if (pos < CAP) \
                    cd[pos] = ((uint64_t)bt << 32) | \
                              (uint32_t)(~(uint32_t)(ibase + j * WW + (P))); \
            }
        EMIT(w0, B.x, 0)
        EMIT(w1, B.y, 1)
        EMIT(w2, B.z, 2)
        EMIT(w3, B.w, 3)
        #undef EMIT
        A = B; B = C;
    }
}

// on-the-fly key for the fallback (never expected on this input)
__device__ uint64_t key_at(const float* __restrict__ hb, int i) {
    float v = hb[i];
    int rem = i & (HW - 1);
    int y = rem >> 7, x = rem & (WW - 1);
    bool mx = true;
    if (y > 0) {
        if (x > 0      && hb[i - WW - 1] > v) mx = false;
        if (              hb[i - WW    ] > v) mx = false;
        if (x < WW - 1 && hb[i - WW + 1] > v) mx = false;
    }
    if (x > 0      && hb[i - 1] > v) mx = false;
    if (x < WW - 1 && hb[i + 1] > v) mx = false;
    if (y < HH - 1) {
        if (x > 0      && hb[i + WW - 1] > v) mx = false;
        if (              hb[i + WW    ] > v) mx = false;
        if (x < WW - 1 && hb[i + WW + 1] > v) mx = false;
    }
    if (!mx) return 0;
    return ((uint64_t)__float_as_uint(sigmoidf(v)) << 32) | (uint32_t)(~(uint32_t)i);
}

// descending bitonic sort of N u64 keys in LDS
template <int N>
__device__ void bitonic_desc(uint64_t* k) {
    for (int kk = 2; kk <= N; kk <<= 1) {
        for (int j = kk >> 1; j > 0; j >>= 1) {
            __syncthreads();
            for (int i = threadIdx.x; i < N; i += blockDim.x) {
                int l = i ^ j;
                if (l > i) {
                    uint64_t a = k[i], b = k[l];
                    bool up = ((i & kk) == 0);
                    if (up ? (a < b) : (a > b)) { k[i] = b; k[l] = a; }
                }
            }
        }
    }
    __syncthreads();
}

// ---- kernel 2: select top-100 per (tensor,batch), with FUSED exact fallback ----
// Common case: count in [K, CAP] -> load fast-path candidates and sort.
// Pathological case: run hist -> threshold -> collect (into LDS keys) here.
__global__ void __launch_bounds__(1024) k_selectfb(
        const uint64_t* __restrict__ cand, const int* __restrict__ ccnt,
        const float* __restrict__ tl, const float* __restrict__ br,
        const float* __restrict__ ct,
        const float* __restrict__ tl_tag, const float* __restrict__ br_tag,
        const float* __restrict__ tl_regr, const float* __restrict__ br_regr,
        const float* __restrict__ ct_regr,
        float* __restrict__ cs, float* __restrict__ cx, float* __restrict__ cy,
        float* __restrict__ ce, int* __restrict__ ccls) {
    __shared__ uint64_t keys[CAP];       // 32 KB
    __shared__ uint32_t lh[NBINS];       // 16 KB (fallback only)
    __shared__ uint32_t csum[1024];      // 4 KB  (fallback only)
    __shared__ int thr_s, cnt_s;
    int tid = threadIdx.x;
    int bc = blockIdx.x; int t = bc >> 3; int b = bc & 7;
    int nf = ccnt[bc * 32];
    bool ok = (nf >= KTOP) && (nf <= CAP);
    int n;
    if (ok) {
        n = nf;
        int lim = (n <= 512) ? 512 : (n <= 2048) ? 2048 : CAP;
        for (int i = tid; i < lim; i += 1024)
            keys[i] = (i < n) ? cand[(size_t)bc * CAP + i] : 0ull;
    } else {
        // ---- exact fallback, fully in-block ----
        const float* heat = (t == 0) ? tl : (t == 1) ? br : ct;
        const float* hb = heat + (size_t)b * CHW;
        for (int i = tid; i < NBINS; i += 1024) lh[i] = 0;
        if (tid == 0) cnt_s = 0;
        __syncthreads();
        for (int i = tid; i < CHW; i += 1024) {
            uint64_t k = key_at(hb, i);
            if (k) atomicAdd(&lh[(uint32_t)(k >> 51)], 1u);
        }
        __syncthreads();
        // threshold: largest bin>=1 with suffix count >= K (bin 0 excluded)
        uint32_t bins[4];
        #pragma unroll
        for (int i = 0; i < 4; ++i) bins[i] = lh[tid * 4 + i];
        if (tid == 0) bins[0] = 0;
        uint32_t s = bins[0] + bins[1] + bins[2] + bins[3];
        csum[tid] = s;
        __syncthreads();
        for (int step = 1; step < 1024; step <<= 1) {
            uint32_t add = (tid + step < 1024) ? csum[tid + step] : 0;
            __syncthreads();
            csum[tid] += add;
            __syncthreads();
        }
        uint32_t inc = csum[tid];
        uint32_t above = (tid < 1023) ? csum[tid + 1] : 0;
        if (tid == 0 && (int)inc < KTOP) thr_s = 1;
        if ((int)above < KTOP && (int)inc >= KTOP) {
            uint32_t cum = above;
            int T = 1;
            #pragma unroll
            for (int i = 3; i >= 0; --i) {
                cum += bins[i];
                if ((int)cum >= KTOP) { T = tid * 4 + i; break; }
            }
            thr_s = T;
        }
        __syncthreads();
        int T = thr_s;
        // collect survivors >= T directly into LDS keys
        for (int i = tid; i < CHW; i += 1024) {
            uint64_t k = key_at(hb, i);
            if (k && (int)(uint32_t)(k >> 51) >= T) {
                int pc = atomicAdd(&cnt_s, 1);
                if (pc < CAP) keys[pc] = k;
            }
        }
        __syncthreads();
        n = cnt_s; if (n > CAP) n = CAP;
        int lim = (n <= 512) ? 512 : (n <= 2048) ? 2048 : CAP;
        for (int i = tid; i < lim; i += 1024) if (i >= n) keys[i] = 0;
    }
    if (n <= 512)       bitonic_desc<512>(keys);
    else if (n <= 2048) bitonic_desc<2048>(keys);
    else                bitonic_desc<CAP>(keys);

    if (tid < KTOP) {
        uint64_t key = keys[tid];
        float s2 = __uint_as_float((uint32_t)(key >> 32));
        uint32_t idx = ~(uint32_t)key;
        int cls = (int)(idx >> 14);
        int rem = (int)(idx & (HW - 1));
        int y = rem >> 7, x = rem & (WW - 1);
        const float* regr = (t == 0) ? tl_regr : (t == 1) ? br_regr : ct_regr;
        float o0 = regr[((size_t)b * 2 + 0) * HW + rem];
        float o1 = regr[((size_t)b * 2 + 1) * HW + rem];
        float emb = 0.f;
        if (t == 0) emb = tl_tag[(size_t)b * HW + rem];
        else if (t == 1) emb = br_tag[(size_t)b * HW + rem];
        int o = bc * KTOP + tid;
        cs[o] = s2;
        cx[o] = (float)x + o0;
        cy[o] = (float)y + o1;
        ce[o] = emb;
        ccls[o] = cls;
    }
}

// ---- kernel 3: fused pairwise scoring + final top-1000 + centers ----
__global__ void __launch_bounds__(1024) k_pairfinal(
        const float* __restrict__ cs, const float* __restrict__ cx,
        const float* __restrict__ cy, const float* __restrict__ ce,
        const int* __restrict__ ccls, float* __restrict__ out) {
    int b = blockIdx.x;
    __shared__ float ts[KTOP], tx[KTOP], ty[KTOP], te[KTOP];
    __shared__ int   tc[KTOP];
    __shared__ float bs_[KTOP], bx[KTOP], by[KTOP], be[KTOP];
    __shared__ int   bcl[KTOP];
    __shared__ uint64_t acc[ACAP];
    __shared__ int aidx[ACAP];
    __shared__ int acnt_s;
    int tid = threadIdx.x;
    if (tid == 0) acnt_s = 0;
    if (tid < KTOP) {
        int o = (0 * NB + b) * KTOP + tid;
        ts[tid] = cs[o]; tx[tid] = cx[o]; ty[tid] = cy[o]; te[tid] = ce[o]; tc[tid] = ccls[o];
    } else if (tid >= 512 && tid < 512 + KTOP) {
        int k = tid - 512;
        int o = (1 * NB + b) * KTOP + k;
        bs_[k] = cs[o]; bx[k] = cx[o]; by[k] = cy[o]; be[k] = ce[o]; bcl[k] = ccls[o];
    }
    __syncthreads();
    for (int p = tid; p < NPAIR; p += 1024) {
        int i = p / KTOP, j = p - i * KTOP;
        bool rej = (tc[i] != bcl[j])
                 | (fabsf(te[i] - be[j]) > 0.5f)
                 | (bx[j] < tx[i])
                 | (by[j] < ty[i]);
        if (!rej) {
            float sc = (ts[i] + bs_[j]) * 0.5f;
            int pos = atomicAdd(&acnt_s, 1);
            if (pos < ACAP)
                acc[pos] = ((uint64_t)__float_as_uint(sc) << 32) | (uint32_t)(~(uint32_t)p);
        }
    }
    __syncthreads();
    int m = acnt_s; if (m > ACAP) m = ACAP;
    if (m <= 256) {
        for (int i = tid; i < 256; i += 1024) if (i >= m) acc[i] = 0;
        bitonic_desc<256>(acc);
    } else {
        for (int i = tid; i < ACAP; i += 1024) if (i >= m) acc[i] = 0;
        bitonic_desc<ACAP>(acc);
    }
    for (int i = tid; i < m; i += 1024) aidx[i] = (int)(~(uint32_t)acc[i]);
    __syncthreads();
    for (int d = tid; d < NDET; d += 1024) {
        int p; float sc;
        if (d < m) {
            p = aidx[d];
            sc = __uint_as_float((uint32_t)(acc[d] >> 32));
        } else {
            // (d-m)-th flat pair-index NOT in accepted set, ascending (stable -1 ties)
            int r = d - m;
            int idx = r;
            for (;;) {
                int c = 0;
                for (int a = 0; a < m; ++a) c += (aidx[a] <= idx) ? 1 : 0;
                int ni = r + c;
                if (ni == idx) break;
                idx = ni;
            }
            p = idx; sc = -1.f;
        }
        int i = p / KTOP, j = p - i * KTOP;
        int ot = (0 * NB + b) * KTOP + i;
        int ob = (1 * NB + b) * KTOP + j;
        float* dr = out + ((size_t)b * NDET + d) * 8;
        dr[0] = cx[ot]; dr[1] = cy[ot]; dr[2] = cx[ob]; dr[3] = cy[ob];
        dr[4] = sc; dr[5] = cs[ot]; dr[6] = cs[ob]; dr[7] = (float)ccls[ot];
    }
    if (tid < KTOP) {
        int oc = (2 * NB + b) * KTOP + tid;
        float* cr = out + (size_t)NB * NDET * 8 + ((size_t)b * KTOP + tid) * 4;
        cr[0] = cx[oc]; cr[1] = cy[oc]; cr[2] = (float)ccls[oc]; cr[3] = cs[oc];
    }
}

extern "C" void kernel_launch(void* const* d_in, const int* in_sizes, int n_in,
                              void* d_out, int out_size, void* d_ws, size_t ws_size,
                              hipStream_t stream) {
    const float* tl_heat = (const float*)d_in[0];
    const float* br_heat = (const float*)d_in[1];
    const float* ct_heat = (const float*)d_in[2];
    const float* tl_tag  = (const float*)d_in[3];
    const float* br_tag  = (const float*)d_in[4];
    const float* tl_regr = (const float*)d_in[5];
    const float* br_regr = (const float*)d_in[6];
    const float* ct_regr = (const float*)d_in[7];

    if (ws_size < (size_t)WS_NEEDED) return;   // ~0.84 MB

    char* ws = (char*)d_ws;
    int*      ccnt = (int*)(ws + OFF_CCNT);
    uint64_t* cand = (uint64_t*)(ws + OFF_CAND);
    float*    cs   = (float*)(ws + OFF_CS);
    float*    cx   = (float*)(ws + OFF_CX);
    float*    cy   = (float*)(ws + OFF_CY);
    float*    ce   = (float*)(ws + OFF_CE);
    int*      ccls = (int*)(ws + OFF_CCLS);

    hipMemsetAsync(ws, 0, ZERO_BYTES, stream);   // ccnt (3 KB)

    k_nms<<<24 * NC * 4, 256, 0, stream>>>(tl_heat, br_heat, ct_heat, cand, ccnt);
    k_selectfb<<<24, 1024, 0, stream>>>(cand, ccnt,
                                        tl_heat, br_heat, ct_heat,
                                        tl_tag, br_tag,
                                        tl_regr, br_regr, ct_regr,
                                        cs, cx, cy, ce, ccls);
    k_pairfinal<<<NB, 1024, 0, stream>>>(cs, cx, cy, ce, ccls, (float*)d_out);
}